// Round 4
// baseline (631.890 us; speedup 1.0000x reference)
//
#include <hip/hip_runtime.h>
#include <stdint.h>

// ---------------------------------------------------------------------------
// VectorQuantizer: argmin_k ||x_n - c_k||^2 + straight-through out + losses.
//
// Token semantics: the reference computes distances in FP32 at magnitude ~256
// (fp32 cell width U ~ 3.05e-5) and argmin resolves ties (codes whose rounded
// distances coincide) to the lowest index. The exact bit-grid depends on the
// reference's summation order (BLAS/SIMD), which is not reproducible here.
// Strategy:
//   * top-4 candidates per row via fast fp32 GEMM on s = ||c||^2 - 2 x.c
//   * exact fp64 re-score of the 4 candidates; token = lowest index among
//     candidates within 0.75*U of the fp64 minimum (hedges the unknown grid:
//     near-cell-width gaps are overwhelmingly coalesced by the ref's fp32
//     rounding and resolve to the lower index).
// ---------------------------------------------------------------------------

#define N_ROWS 16384
#define DIM    256
#define KCODES 4096
#define NCHUNK 4
#define KC     (KCODES / NCHUNK)   // 1024 codes per K-chunk
#define TM     128                 // rows per block tile
#define TN     128                 // codes per block tile
#define DC     32                  // D-chunk staged in LDS
#define NKT    (KC / TN)           // 8 code tiles per chunk
#define NDC    (DIM / DC)          // 8 D-chunks
#define PADM   (TM + 4)            // 132: keeps 16B alignment, breaks pow2 strides
#define PADN   (TN + 4)

// order-preserving float->uint key for atomicMin
__device__ __forceinline__ unsigned fkey(float f) {
    unsigned b = __float_as_uint(f);
    return (b & 0x80000000u) ? ~b : (b | 0x80000000u);
}
__device__ __forceinline__ float fkey_inv(unsigned k) {
    unsigned b = (k & 0x80000000u) ? (k ^ 0x80000000u) : ~k;
    return __uint_as_float(b);
}

// sorted top-4 insert by (value, index) lexicographic
__device__ __forceinline__ void ins4(float w, int j, float v[4], int id[4]) {
    if (w < v[3] || (w == v[3] && j < id[3])) {
        v[3] = w; id[3] = j;
#pragma unroll
        for (int k = 3; k > 0; --k) {
            if (v[k] < v[k-1] || (v[k] == v[k-1] && id[k] < id[k-1])) {
                float tv = v[k]; v[k] = v[k-1]; v[k-1] = tv;
                int ti = id[k]; id[k] = id[k-1]; id[k-1] = ti;
            }
        }
    }
}

__global__ void vq_init_kernel(unsigned* __restrict__ colmin_g,
                               unsigned* __restrict__ active,
                               double* __restrict__ accum) {
    int i = blockIdx.x * 256 + threadIdx.x;
    if (i < KCODES) { colmin_g[i] = 0xFFFFFFFFu; active[i] = 0u; }
    if (i == 0) accum[0] = 0.0;
}

// ||row||^2 (fp32, numpy-scalar-pairwise order; used only for colmin and the
// continuous candidate ranking -- not for the final token decision)
__global__ __launch_bounds__(256) void vq_sq_np_kernel(const float* __restrict__ x,
                                                       const float* __restrict__ cb,
                                                       float* __restrict__ xsq,
                                                       float* __restrict__ csq) {
#pragma clang fp contract(off)
    const int g    = threadIdx.x >> 4;   // row within block, 0..15
    const int l    = threadIdx.x & 15;
    const int half = l >> 3;
    const int j    = l & 7;
    const int r    = blockIdx.x * 16 + g;
    const float* base = (r < N_ROWS) ? (x + (size_t)r * DIM)
                                     : (cb + (size_t)(r - N_ROWS) * DIM);
    const float* p = base + half * 128 + j;
    float acc = 0.0f;
#pragma unroll
    for (int t = 0; t < 16; ++t) {
        float v  = p[8 * t];
        float sq = v * v;
        acc = acc + sq;
    }
    acc = acc + __shfl_xor(acc, 1);
    acc = acc + __shfl_xor(acc, 2);
    acc = acc + __shfl_xor(acc, 4);
    acc = acc + __shfl_xor(acc, 8);  // half0 + half1
    if (l == 0) {
        if (r < N_ROWS) xsq[r] = acc; else csq[r - N_ROWS] = acc;
    }
}

// Main distance GEMM. grid = (N_ROWS/TM, NCHUNK), block = 256.
// Per block: TM rows x KC codes, looping NKT code tiles of TN.
// Emits per-row TOP-4 candidates (by continuous score) per chunk.
__global__ __launch_bounds__(256, 2) void vq_gemm_kernel(
        const float* __restrict__ x, const float* __restrict__ cb,
        const float* __restrict__ xsq, const float* __restrict__ csq,
        unsigned* __restrict__ colmin_g, uint4* __restrict__ top4_out) {
    __shared__ __align__(16) char smem_raw[(DC * PADM + DC * PADN) * 4 + TN * 4];
    float (*xs)[PADM] = (float (*)[PADM])smem_raw;
    float (*cs)[PADN] = (float (*)[PADN])(smem_raw + DC * PADM * 4);
    unsigned* colmin_l = (unsigned*)(smem_raw + (DC * PADM + DC * PADN) * 4);
    unsigned (*top2s)[16][4] = (unsigned (*)[16][4])smem_raw;  // 32KB, reused at end

    const int t  = threadIdx.x;
    const int tc = t & 15;       // code group 0..15  (8 codes each)
    const int tr = t >> 4;       // row group  0..15  (8 rows each)
    const int row0  = blockIdx.x * TM;
    const int code0 = blockIdx.y * KC;

    float rv1[8], rv2[8], xsqr[8];
    int   ri1[8], ri2[8];
#pragma unroll
    for (int r = 0; r < 8; ++r) {
        rv1[r] = 3.4e38f; rv2[r] = 3.4e38f;
        ri1[r] = 0x7FFFFFFF; ri2[r] = 0x7FFFFFFF;
        xsqr[r] = xsq[row0 + tr * 8 + r];
    }

    for (int kt = 0; kt < NKT; ++kt) {
        const int cb0 = code0 + kt * TN;
        float acc[8][8];
#pragma unroll
        for (int r = 0; r < 8; ++r)
#pragma unroll
            for (int c = 0; c < 8; ++c) acc[r][c] = 0.0f;

        for (int dc = 0; dc < NDC; ++dc) {
            const int d0 = dc * DC;
#pragma unroll
            for (int i = 0; i < 4; ++i) {
                int q = i * 256 + t;
                int row = q >> 3, dseg = q & 7;
                float4 xv = *(const float4*)(x  + (size_t)(row0 + row) * DIM + d0 + dseg * 4);
                float4 cv = *(const float4*)(cb + (size_t)(cb0 + row) * DIM + d0 + dseg * 4);
                xs[dseg * 4 + 0][row] = xv.x; xs[dseg * 4 + 1][row] = xv.y;
                xs[dseg * 4 + 2][row] = xv.z; xs[dseg * 4 + 3][row] = xv.w;
                cs[dseg * 4 + 0][row] = cv.x; cs[dseg * 4 + 1][row] = cv.y;
                cs[dseg * 4 + 2][row] = cv.z; cs[dseg * 4 + 3][row] = cv.w;
            }
            __syncthreads();
#pragma unroll 8
            for (int d = 0; d < DC; ++d) {
                float4 xa = *(const float4*)&xs[d][tr * 8];
                float4 xb = *(const float4*)&xs[d][tr * 8 + 4];
                float4 ca = *(const float4*)&cs[d][tc * 8];
                float4 cc = *(const float4*)&cs[d][tc * 8 + 4];
                float xf[8] = {xa.x, xa.y, xa.z, xa.w, xb.x, xb.y, xb.z, xb.w};
                float cf[8] = {ca.x, ca.y, ca.z, ca.w, cc.x, cc.y, cc.z, cc.w};
#pragma unroll
                for (int r = 0; r < 8; ++r)
#pragma unroll
                    for (int c = 0; c < 8; ++c)
                        acc[r][c] = fmaf(xf[r], cf[c], acc[r][c]);
            }
            __syncthreads();
        }

        // epilogue: score = csq - 2*cross; per-thread top2; column-min of dist
        float4 qa = *(const float4*)&csq[cb0 + tc * 8];
        float4 qb = *(const float4*)&csq[cb0 + tc * 8 + 4];
        float cs8[8] = {qa.x, qa.y, qa.z, qa.w, qb.x, qb.y, qb.z, qb.w};
        if (t < TN) colmin_l[t] = 0xFFFFFFFFu;
        __syncthreads();
#pragma unroll
        for (int uu = 0; uu < 8; ++uu) {
            const int idx = cb0 + tc * 8 + uu;
            float dmin = 3.4e38f;
#pragma unroll
            for (int r = 0; r < 8; ++r) {
                float s = fmaf(-2.0f, acc[r][uu], cs8[uu]);
                if (s < rv1[r]) { rv2[r] = rv1[r]; ri2[r] = ri1[r]; rv1[r] = s; ri1[r] = idx; }
                else if (s < rv2[r]) { rv2[r] = s; ri2[r] = idx; }
                dmin = fminf(dmin, xsqr[r] + s);
            }
            atomicMin(&colmin_l[tc * 8 + uu], fkey(dmin));
        }
        __syncthreads();
        if (t < TN) atomicMin(&colmin_g[cb0 + t], colmin_l[t]);
        __syncthreads();
    }

    // per-group top-2 -> LDS, then merge to per-row TOP-4 for this chunk
#pragma unroll
    for (int r = 0; r < 8; ++r) {
        unsigned* e = top2s[tr * 8 + r][tc];
        e[0] = __float_as_uint(rv1[r]); e[1] = (unsigned)ri1[r];
        e[2] = __float_as_uint(rv2[r]); e[3] = (unsigned)ri2[r];
    }
    __syncthreads();
    if (t < TM) {
        float v[4]  = {3.4e38f, 3.4e38f, 3.4e38f, 3.4e38f};
        int   id[4] = {0x7FFFFFFF, 0x7FFFFFFF, 0x7FFFFFFF, 0x7FFFFFFF};
        for (int j = 0; j < 16; ++j) {
            unsigned* e = top2s[t][j];
            ins4(__uint_as_float(e[0]), (int)e[1], v, id);
            ins4(__uint_as_float(e[2]), (int)e[3], v, id);
        }
        size_t base = ((size_t)blockIdx.y * N_ROWS + row0 + t) * 2;
        top4_out[base + 0] = make_uint4(__float_as_uint(v[0]), (unsigned)id[0],
                                        __float_as_uint(v[1]), (unsigned)id[1]);
        top4_out[base + 1] = make_uint4(__float_as_uint(v[2]), (unsigned)id[2],
                                        __float_as_uint(v[3]), (unsigned)id[3]);
    }
}

// Merge 4 chunks' top-4 -> global top-4; exact fp64 distances for the 4
// candidates; token = lowest index within 0.75*ulp_fp32(Dmin) of the minimum.
__global__ __launch_bounds__(256) void vq_refine_kernel(
        const float* __restrict__ x, const float* __restrict__ cb,
        const uint4* __restrict__ top4, int* __restrict__ tokens,
        unsigned* __restrict__ active) {
    const int lane = threadIdx.x & 63;
    const int row  = blockIdx.x * 4 + (threadIdx.x >> 6);

    float v[4]  = {3.4e38f, 3.4e38f, 3.4e38f, 3.4e38f};
    int   id[4] = {0x7FFFFFFF, 0x7FFFFFFF, 0x7FFFFFFF, 0x7FFFFFFF};
#pragma unroll
    for (int c = 0; c < NCHUNK; ++c) {
#pragma unroll
        for (int h = 0; h < 2; ++h) {
            uint4 e = top4[((size_t)c * N_ROWS + row) * 2 + h];
            ins4(__uint_as_float(e.x), (int)e.y, v, id);
            ins4(__uint_as_float(e.z), (int)e.w, v, id);
        }
    }

    // exact fp64 distances for the 4 candidates (wave-parallel over D)
    float4 xv = ((const float4*)(x + (size_t)row * DIM))[lane];
    double xs64 = (double)xv.x * xv.x + (double)xv.y * xv.y
                + (double)xv.z * xv.z + (double)xv.w * xv.w;
    double dd[4], cc2[4];
#pragma unroll
    for (int k = 0; k < 4; ++k) {
        float4 cv = ((const float4*)(cb + (size_t)id[k] * DIM))[lane];
        dd[k]  = (double)xv.x * cv.x + (double)xv.y * cv.y
               + (double)xv.z * cv.z + (double)xv.w * cv.w;
        cc2[k] = (double)cv.x * cv.x + (double)cv.y * cv.y
               + (double)cv.z * cv.z + (double)cv.w * cv.w;
    }
    for (int o = 32; o; o >>= 1) {
        xs64 += __shfl_down(xs64, o);
#pragma unroll
        for (int k = 0; k < 4; ++k) {
            dd[k]  += __shfl_down(dd[k], o);
            cc2[k] += __shfl_down(cc2[k], o);
        }
    }
    if (lane == 0) {
        double D[4];
        double Dmin = 1e300;
#pragma unroll
        for (int k = 0; k < 4; ++k) {
            D[k] = xs64 + cc2[k] - 2.0 * dd[k];
            Dmin = fmin(Dmin, D[k]);
        }
        // fp32 cell width at Dmin (Dmin ~ 150..400 > 0)
        int e2; frexp(Dmin, &e2);                 // Dmin = m * 2^e2, m in [0.5,1)
        double U   = ldexp(1.0, e2 - 1 - 23);     // ulp_fp32(Dmin)
        double thr = Dmin + 0.75 * U;
        int tok = 0x7FFFFFFF;
#pragma unroll
        for (int k = 0; k < 4; ++k)
            if (D[k] <= thr && id[k] < tok) tok = id[k];
        tokens[row] = tok;
        active[tok] = 1u;
    }
}

// gather codebook rows to out + accumulate sum((emb-x)^2)
__global__ __launch_bounds__(256) void vq_out_kernel(
        const float* __restrict__ x, const float* __restrict__ cb,
        const int* __restrict__ tokens, float* __restrict__ out,
        double* __restrict__ accum) {
    __shared__ double wsum[4];
    const int w = threadIdx.x >> 6, lane = threadIdx.x & 63;
    const int row = blockIdx.x * 4 + w;
    const int tok = tokens[row];
    float4 xv = ((const float4*)(x + (size_t)row * DIM))[lane];
    float4 cv = ((const float4*)(cb + (size_t)tok * DIM))[lane];
    ((float4*)out)[(size_t)row * 64 + lane] = cv;
    float dx = cv.x - xv.x, dy = cv.y - xv.y, dz = cv.z - xv.z, dw = cv.w - xv.w;
    float s = dx * dx + dy * dy + dz * dz + dw * dw;
    for (int o = 32; o; o >>= 1) s += __shfl_down(s, o);
    if (lane == 0) wsum[w] = (double)s;
    __syncthreads();
    if (threadIdx.x == 0) atomicAdd(accum, wsum[0] + wsum[1] + wsum[2] + wsum[3]);
}

// entropy term over inactive classes + final scalar loss
__global__ __launch_bounds__(256) void vq_final_kernel(
        const unsigned* __restrict__ colmin_g, const unsigned* __restrict__ active,
        const double* __restrict__ accum, float* __restrict__ out) {
    __shared__ double red[256];
    double s = 0.0;
    for (int k = threadIdx.x; k < KCODES; k += 256)
        if (active[k] == 0u) s += (double)fkey_inv(colmin_g[k]);
    red[threadIdx.x] = s;
    __syncthreads();
    for (int o = 128; o; o >>= 1) {
        if (threadIdx.x < o) red[threadIdx.x] += red[threadIdx.x + o];
        __syncthreads();
    }
    if (threadIdx.x == 0) {
        double loss = 1.25 * (accum[0] / (double)((size_t)N_ROWS * DIM))
                    + 0.02 * (red[0] / (double)KCODES);
        out[(size_t)N_ROWS * DIM] = (float)loss;
    }
}

extern "C" void kernel_launch(void* const* d_in, const int* in_sizes, int n_in,
                              void* d_out, int out_size, void* d_ws, size_t ws_size,
                              hipStream_t stream) {
    const float* x  = (const float*)d_in[0];   // [16384, 256]
    const float* cb = (const float*)d_in[1];   // [4096, 256]
    float* out = (float*)d_out;                // [16384*256] ++ [1] loss

    char* ws = (char*)d_ws;
    float*    xsq    = (float*)(ws + 0);            // 65536 B
    float*    csq    = (float*)(ws + 65536);        // 16384 B
    unsigned* colmin = (unsigned*)(ws + 81920);     // 16384 B
    unsigned* active = (unsigned*)(ws + 98304);     // 16384 B
    int*      tokens = (int*)(ws + 114688);         // 65536 B
    double*   accum  = (double*)(ws + 180224);      // 256 B
    uint4*    top4   = (uint4*)(ws + 180480);       // 4*16384*32 B = 2 MB

    vq_init_kernel<<<16, 256, 0, stream>>>(colmin, active, accum);
    vq_sq_np_kernel<<<(N_ROWS + KCODES) / 16, 256, 0, stream>>>(x, cb, xsq, csq);
    vq_gemm_kernel<<<dim3(N_ROWS / TM, NCHUNK), 256, 0, stream>>>(x, cb, xsq, csq, colmin, top4);
    vq_refine_kernel<<<N_ROWS / 4, 256, 0, stream>>>(x, cb, top4, tokens, active);
    vq_out_kernel<<<N_ROWS / 4, 256, 0, stream>>>(x, cb, tokens, out, accum);
    vq_final_kernel<<<1, 256, 0, stream>>>(colmin, active, accum, out);
}

// Round 5
// 374.921 us; speedup vs baseline: 1.6854x; 1.6854x over previous
//
#include <hip/hip_runtime.h>
#include <stdint.h>

// ---------------------------------------------------------------------------
// VectorQuantizer: argmin_k ||x_n - c_k||^2 + straight-through out + losses.
//
// Token semantics (R4-verified): top-4 candidates per row by continuous score
// s = ||c||^2 - 2 x.c, then exact fp64 re-score of the 4; token = lowest index
// within 0.75*ulp_fp32(Dmin) of the minimum (hedges the reference's fp32
// rounding grid / tie-to-lowest-index behavior).
//
// R5 change: candidate GEMM moved from fp32 VALU (528us, MfmaUtil=0) to bf16
// MFMA with hi/lo split: x = xh + xl (bf16 + bf16 residual), cross =
// xh*ch + xh*cl + xl*ch (dropped ll term ~5e-7). Score error <= ~5e-6, far
// below the tie window (3e-5); refine semantics unchanged.
// ---------------------------------------------------------------------------

#define N_ROWS 16384
#define DIM    256
#define KCODES 4096
#define NCHUNK 4
#define KC     (KCODES / NCHUNK)   // 1024 codes per K-chunk
#define TM     128                 // rows per block tile
#define TN     128                 // codes per code-tile
#define BK     32                  // K-chunk per MFMA step
#define NKT    (KC / TN)           // 8 code tiles per chunk
#define NDC    (DIM / BK)          // 8 K-steps
#define LROW   40                  // padded LDS row stride (halfs): 80B, breaks conflicts

typedef float f32x4 __attribute__((ext_vector_type(4)));
typedef short s16x8 __attribute__((ext_vector_type(8)));

// order-preserving float->uint key for atomicMin
__device__ __forceinline__ unsigned fkey(float f) {
    unsigned b = __float_as_uint(f);
    return (b & 0x80000000u) ? ~b : (b | 0x80000000u);
}
__device__ __forceinline__ float fkey_inv(unsigned k) {
    unsigned b = (k & 0x80000000u) ? (k ^ 0x80000000u) : ~k;
    return __uint_as_float(b);
}

__device__ __forceinline__ unsigned short f2bf(float f) {   // round-to-nearest-even
    unsigned u = __float_as_uint(f);
    unsigned r = u + 0x7FFFu + ((u >> 16) & 1u);
    return (unsigned short)(r >> 16);
}
__device__ __forceinline__ float bf2f(unsigned short h) {
    return __uint_as_float(((unsigned)h) << 16);
}

// sorted top-4 insert by (value, index) lexicographic
__device__ __forceinline__ void ins4(float w, int j, float v[4], int id[4]) {
    if (w < v[3] || (w == v[3] && j < id[3])) {
        v[3] = w; id[3] = j;
#pragma unroll
        for (int k = 3; k > 0; --k) {
            if (v[k] < v[k-1] || (v[k] == v[k-1] && id[k] < id[k-1])) {
                float tv = v[k]; v[k] = v[k-1]; v[k-1] = tv;
                int ti = id[k]; id[k] = id[k-1]; id[k-1] = ti;
            }
        }
    }
}

__global__ void vq_init_kernel(unsigned* __restrict__ colmin_g,
                               unsigned* __restrict__ active,
                               double* __restrict__ accum) {
    int i = blockIdx.x * 256 + threadIdx.x;
    if (i < KCODES) { colmin_g[i] = 0xFFFFFFFFu; active[i] = 0u; }
    if (i == 0) accum[0] = 0.0;
}

// split f32 -> bf16 hi + bf16(residual) lo, for x and codebook
__global__ __launch_bounds__(256) void vq_prep_kernel(
        const float* __restrict__ x, const float* __restrict__ cb,
        unsigned short* __restrict__ xh, unsigned short* __restrict__ xl,
        unsigned short* __restrict__ ch, unsigned short* __restrict__ cl) {
    const size_t NX = (size_t)N_ROWS * DIM;
    size_t i = ((size_t)blockIdx.x * 256 + threadIdx.x) * 4;
    const float* src; unsigned short *ph, *pl; size_t off;
    if (i < NX) { src = x;  ph = xh; pl = xl; off = i; }
    else        { src = cb; ph = ch; pl = cl; off = i - NX; }
    float4 v = *(const float4*)(src + off);
    ushort4 h, l;
    h.x = f2bf(v.x); l.x = f2bf(v.x - bf2f(h.x));
    h.y = f2bf(v.y); l.y = f2bf(v.y - bf2f(h.y));
    h.z = f2bf(v.z); l.z = f2bf(v.z - bf2f(h.z));
    h.w = f2bf(v.w); l.w = f2bf(v.w - bf2f(h.w));
    *(ushort4*)(ph + off) = h;
    *(ushort4*)(pl + off) = l;
}

// ||row||^2 (fp32; feeds colmin entropy term + epilogue score constant)
__global__ __launch_bounds__(256) void vq_sq_np_kernel(const float* __restrict__ x,
                                                       const float* __restrict__ cb,
                                                       float* __restrict__ xsq,
                                                       float* __restrict__ csq) {
#pragma clang fp contract(off)
    const int g    = threadIdx.x >> 4;
    const int l    = threadIdx.x & 15;
    const int half = l >> 3;
    const int j    = l & 7;
    const int r    = blockIdx.x * 16 + g;
    const float* base = (r < N_ROWS) ? (x + (size_t)r * DIM)
                                     : (cb + (size_t)(r - N_ROWS) * DIM);
    const float* p = base + half * 128 + j;
    float acc = 0.0f;
#pragma unroll
    for (int t = 0; t < 16; ++t) {
        float v  = p[8 * t];
        float sq = v * v;
        acc = acc + sq;
    }
    acc = acc + __shfl_xor(acc, 1);
    acc = acc + __shfl_xor(acc, 2);
    acc = acc + __shfl_xor(acc, 4);
    acc = acc + __shfl_xor(acc, 8);
    if (l == 0) {
        if (r < N_ROWS) xsq[r] = acc; else csq[r - N_ROWS] = acc;
    }
}

// MFMA candidate GEMM. grid = (N_ROWS/TM, NCHUNK), block = 256 (4 waves, 2x2).
// Per block: TM rows x KC codes via NKT code tiles of TN; per tile fused
// epilogue: per-row top-2 -> running top-4 (t<128) and per-code column-min.
__global__ __launch_bounds__(256, 2) void vq_gemm_kernel(
        const unsigned short* __restrict__ xh_g, const unsigned short* __restrict__ xl_g,
        const unsigned short* __restrict__ ch_g, const unsigned short* __restrict__ cl_g,
        const float* __restrict__ xsq, const float* __restrict__ csq,
        unsigned* __restrict__ colmin_g, uint4* __restrict__ top4_out) {
    __shared__ __align__(16) unsigned short tiles[4 * 128 * LROW];  // 40960 B
    __shared__ float    xsq_l[128];
    __shared__ unsigned colmin_l[128];
    uint4* mrg = (uint4*)tiles;            // [128][16], aliases tiles between K-loops

    unsigned short* xh_t = tiles;
    unsigned short* xl_t = tiles + 128 * LROW;
    unsigned short* ch_t = tiles + 2 * 128 * LROW;
    unsigned short* cl_t = tiles + 3 * 128 * LROW;

    const int t = threadIdx.x;
    const int wave = t >> 6, lane = t & 63, quad = lane >> 4, L = lane & 15;
    const int whalf = wave >> 1, chalf = wave & 1;
    const int row0  = blockIdx.x * TM;
    const int code0 = blockIdx.y * KC;

    if (t < 128) { xsq_l[t] = xsq[row0 + t]; colmin_l[t] = 0xFFFFFFFFu; }
    __syncthreads();
    float xsqr[16];
#pragma unroll
    for (int mt = 0; mt < 4; ++mt)
#pragma unroll
        for (int r = 0; r < 4; ++r)
            xsqr[mt * 4 + r] = xsq_l[whalf * 64 + mt * 16 + quad * 4 + r];

    // staging mapping: thread -> (row, 16-half chunk)
    const int sr = t >> 1, sh = t & 1;
    const size_t xbase = (size_t)(row0 + sr) * DIM + sh * 16;
    const int so = sr * LROW + sh * 16;

    float vtop[4]; int itop[4];            // running per-row top4 (t<128)
#pragma unroll
    for (int k = 0; k < 4; ++k) { vtop[k] = 3.4e38f; itop[k] = 0x7FFFFFFF; }

    const f32x4 zero4 = {0.0f, 0.0f, 0.0f, 0.0f};

    for (int kt = 0; kt < NKT; ++kt) {
        const int cb0 = code0 + kt * TN;
        const size_t cbase = (size_t)(cb0 + sr) * DIM + sh * 16;
        f32x4 acc[4][4];
#pragma unroll
        for (int mt = 0; mt < 4; ++mt)
#pragma unroll
            for (int nt = 0; nt < 4; ++nt) acc[mt][nt] = zero4;

        for (int dc = 0; dc < NDC; ++dc) {
            __syncthreads();
            const size_t xo = xbase + dc * BK;
            const size_t co = cbase + dc * BK;
            uint4 a0 = *(const uint4*)(xh_g + xo), a1 = *(const uint4*)(xh_g + xo + 8);
            uint4 b0 = *(const uint4*)(xl_g + xo), b1 = *(const uint4*)(xl_g + xo + 8);
            uint4 c0 = *(const uint4*)(ch_g + co), c1 = *(const uint4*)(ch_g + co + 8);
            uint4 d0 = *(const uint4*)(cl_g + co), d1 = *(const uint4*)(cl_g + co + 8);
            *(uint4*)(xh_t + so) = a0; *(uint4*)(xh_t + so + 8) = a1;
            *(uint4*)(xl_t + so) = b0; *(uint4*)(xl_t + so + 8) = b1;
            *(uint4*)(ch_t + so) = c0; *(uint4*)(ch_t + so + 8) = c1;
            *(uint4*)(cl_t + so) = d0; *(uint4*)(cl_t + so + 8) = d1;
            __syncthreads();

            s16x8 axh[4], axl[4], bch[4], bcl[4];
#pragma unroll
            for (int mt = 0; mt < 4; ++mt) {
                const int ao = (whalf * 64 + mt * 16 + L) * LROW + quad * 8;
                axh[mt] = *(const s16x8*)(xh_t + ao);
                axl[mt] = *(const s16x8*)(xl_t + ao);
            }
#pragma unroll
            for (int nt = 0; nt < 4; ++nt) {
                const int bo = (chalf * 64 + nt * 16 + L) * LROW + quad * 8;
                bch[nt] = *(const s16x8*)(ch_t + bo);
                bcl[nt] = *(const s16x8*)(cl_t + bo);
            }
#pragma unroll
            for (int mt = 0; mt < 4; ++mt)
#pragma unroll
                for (int nt = 0; nt < 4; ++nt) {
                    acc[mt][nt] = __builtin_amdgcn_mfma_f32_16x16x32_bf16(
                        axh[mt], bch[nt], acc[mt][nt], 0, 0, 0);
                    acc[mt][nt] = __builtin_amdgcn_mfma_f32_16x16x32_bf16(
                        axh[mt], bcl[nt], acc[mt][nt], 0, 0, 0);
                    acc[mt][nt] = __builtin_amdgcn_mfma_f32_16x16x32_bf16(
                        axl[mt], bch[nt], acc[mt][nt], 0, 0, 0);
                }
        }

        // ---- epilogue: score = csq - 2*cross; top-2/row; column-min ----
        __syncthreads();   // tiles no longer read -> mrg aliasing safe
        float csq4[4]; int code4[4];
#pragma unroll
        for (int nt = 0; nt < 4; ++nt) {
            code4[nt] = cb0 + chalf * 64 + nt * 16 + L;
            csq4[nt]  = csq[code4[nt]];
        }
        float cmin[4] = {3.4e38f, 3.4e38f, 3.4e38f, 3.4e38f};
#pragma unroll
        for (int mt = 0; mt < 4; ++mt) {
#pragma unroll
            for (int reg = 0; reg < 4; ++reg) {
                float v1 = 3.4e38f, v2 = 3.4e38f;
                int   i1 = 0x7FFFFFFF, i2 = 0x7FFFFFFF;
#pragma unroll
                for (int nt = 0; nt < 4; ++nt) {
                    float s = fmaf(-2.0f, acc[mt][nt][reg], csq4[nt]);
                    if (s < v1)      { v2 = v1; i2 = i1; v1 = s; i1 = code4[nt]; }
                    else if (s < v2) { v2 = s; i2 = code4[nt]; }
                    cmin[nt] = fminf(cmin[nt], xsqr[mt * 4 + reg] + s);
                }
                // merge with lane^1 (adjacent col lane, same row)
                float w1 = __shfl_xor(v1, 1), w2 = __shfl_xor(v2, 1);
                int   j1 = __shfl_xor(i1, 1), j2 = __shfl_xor(i2, 1);
                if (w1 < v1 || (w1 == v1 && j1 < i1)) { v2 = v1; i2 = i1; v1 = w1; i1 = j1; }
                else if (w1 < v2 || (w1 == v2 && j1 < i2)) { v2 = w1; i2 = j1; }
                if (w2 < v1 || (w2 == v1 && j2 < i1)) { v2 = v1; i2 = i1; v1 = w2; i1 = j2; }
                else if (w2 < v2 || (w2 == v2 && j2 < i2)) { v2 = w2; i2 = j2; }
                if ((L & 1) == 0) {
                    const int rowl = whalf * 64 + mt * 16 + quad * 4 + reg;
                    mrg[rowl * 16 + chalf * 8 + (L >> 1)] =
                        make_uint4(__float_as_uint(v1), (unsigned)i1,
                                   __float_as_uint(v2), (unsigned)i2);
                }
            }
        }
#pragma unroll
        for (int nt = 0; nt < 4; ++nt)
            atomicMin(&colmin_l[chalf * 64 + nt * 16 + L], fkey(cmin[nt]));
        __syncthreads();
        if (t < 128) {
#pragma unroll
            for (int j = 0; j < 16; ++j) {
                uint4 e = mrg[t * 16 + j];
                ins4(__uint_as_float(e.x), (int)e.y, vtop, itop);
                ins4(__uint_as_float(e.z), (int)e.w, vtop, itop);
            }
            atomicMin(&colmin_g[cb0 + t], colmin_l[t]);
            colmin_l[t] = 0xFFFFFFFFu;
        }
        __syncthreads();
    }

    if (t < 128) {
        size_t base = ((size_t)blockIdx.y * N_ROWS + row0 + t) * 2;
        top4_out[base + 0] = make_uint4(__float_as_uint(vtop[0]), (unsigned)itop[0],
                                        __float_as_uint(vtop[1]), (unsigned)itop[1]);
        top4_out[base + 1] = make_uint4(__float_as_uint(vtop[2]), (unsigned)itop[2],
                                        __float_as_uint(vtop[3]), (unsigned)itop[3]);
    }
}

// Merge 4 chunks' top-4 -> global top-4; exact fp64 distances for the 4
// candidates; token = lowest index within 0.75*ulp_fp32(Dmin) of the minimum.
__global__ __launch_bounds__(256) void vq_refine_kernel(
        const float* __restrict__ x, const float* __restrict__ cb,
        const uint4* __restrict__ top4, int* __restrict__ tokens,
        unsigned* __restrict__ active) {
    const int lane = threadIdx.x & 63;
    const int row  = blockIdx.x * 4 + (threadIdx.x >> 6);

    float v[4]  = {3.4e38f, 3.4e38f, 3.4e38f, 3.4e38f};
    int   id[4] = {0x7FFFFFFF, 0x7FFFFFFF, 0x7FFFFFFF, 0x7FFFFFFF};
#pragma unroll
    for (int c = 0; c < NCHUNK; ++c) {
#pragma unroll
        for (int h = 0; h < 2; ++h) {
            uint4 e = top4[((size_t)c * N_ROWS + row) * 2 + h];
            ins4(__uint_as_float(e.x), (int)e.y, v, id);
            ins4(__uint_as_float(e.z), (int)e.w, v, id);
        }
    }

    float4 xv = ((const float4*)(x + (size_t)row * DIM))[lane];
    double xs64 = (double)xv.x * xv.x + (double)xv.y * xv.y
                + (double)xv.z * xv.z + (double)xv.w * xv.w;
    double dd[4], cc2[4];
#pragma unroll
    for (int k = 0; k < 4; ++k) {
        float4 cv = ((const float4*)(cb + (size_t)id[k] * DIM))[lane];
        dd[k]  = (double)xv.x * cv.x + (double)xv.y * cv.y
               + (double)xv.z * cv.z + (double)xv.w * cv.w;
        cc2[k] = (double)cv.x * cv.x + (double)cv.y * cv.y
               + (double)cv.z * cv.z + (double)cv.w * cv.w;
    }
    for (int o = 32; o; o >>= 1) {
        xs64 += __shfl_down(xs64, o);
#pragma unroll
        for (int k = 0; k < 4; ++k) {
            dd[k]  += __shfl_down(dd[k], o);
            cc2[k] += __shfl_down(cc2[k], o);
        }
    }
    if (lane == 0) {
        double D[4];
        double Dmin = 1e300;
#pragma unroll
        for (int k = 0; k < 4; ++k) {
            D[k] = xs64 + cc2[k] - 2.0 * dd[k];
            Dmin = fmin(Dmin, D[k]);
        }
        int e2; frexp(Dmin, &e2);
        double U   = ldexp(1.0, e2 - 1 - 23);     // ulp_fp32(Dmin)
        double thr = Dmin + 0.75 * U;
        int tok = 0x7FFFFFFF;
#pragma unroll
        for (int k = 0; k < 4; ++k)
            if (D[k] <= thr && id[k] < tok) tok = id[k];
        tokens[row] = tok;
        active[tok] = 1u;
    }
}

// gather codebook rows to out + accumulate sum((emb-x)^2)
__global__ __launch_bounds__(256) void vq_out_kernel(
        const float* __restrict__ x, const float* __restrict__ cb,
        const int* __restrict__ tokens, float* __restrict__ out,
        double* __restrict__ accum) {
    __shared__ double wsum[4];
    const int w = threadIdx.x >> 6, lane = threadIdx.x & 63;
    const int row = blockIdx.x * 4 + w;
    const int tok = tokens[row];
    float4 xv = ((const float4*)(x + (size_t)row * DIM))[lane];
    float4 cv = ((const float4*)(cb + (size_t)tok * DIM))[lane];
    ((float4*)out)[(size_t)row * 64 + lane] = cv;
    float dx = cv.x - xv.x, dy = cv.y - xv.y, dz = cv.z - xv.z, dw = cv.w - xv.w;
    float s = dx * dx + dy * dy + dz * dz + dw * dw;
    for (int o = 32; o; o >>= 1) s += __shfl_down(s, o);
    if (lane == 0) wsum[w] = (double)s;
    __syncthreads();
    if (threadIdx.x == 0) atomicAdd(accum, wsum[0] + wsum[1] + wsum[2] + wsum[3]);
}

// entropy term over inactive classes + final scalar loss
__global__ __launch_bounds__(256) void vq_final_kernel(
        const unsigned* __restrict__ colmin_g, const unsigned* __restrict__ active,
        const double* __restrict__ accum, float* __restrict__ out) {
    __shared__ double red[256];
    double s = 0.0;
    for (int k = threadIdx.x; k < KCODES; k += 256)
        if (active[k] == 0u) s += (double)fkey_inv(colmin_g[k]);
    red[threadIdx.x] = s;
    __syncthreads();
    for (int o = 128; o; o >>= 1) {
        if (threadIdx.x < o) red[threadIdx.x] += red[threadIdx.x + o];
        __syncthreads();
    }
    if (threadIdx.x == 0) {
        double loss = 1.25 * (accum[0] / (double)((size_t)N_ROWS * DIM))
                    + 0.02 * (red[0] / (double)KCODES);
        out[(size_t)N_ROWS * DIM] = (float)loss;
    }
}

extern "C" void kernel_launch(void* const* d_in, const int* in_sizes, int n_in,
                              void* d_out, int out_size, void* d_ws, size_t ws_size,
                              hipStream_t stream) {
    const float* x  = (const float*)d_in[0];   // [16384, 256]
    const float* cb = (const float*)d_in[1];   // [4096, 256]
    float* out = (float*)d_out;                // [16384*256] ++ [1] loss

    char* ws = (char*)d_ws;
    float*    xsq    = (float*)(ws + 0);              // 65536 B
    float*    csq    = (float*)(ws + 65536);          // 16384 B
    unsigned* colmin = (unsigned*)(ws + 81920);       // 16384 B
    unsigned* active = (unsigned*)(ws + 98304);       // 16384 B
    int*      tokens = (int*)(ws + 114688);           // 65536 B
    double*   accum  = (double*)(ws + 180224);        // 256 B
    uint4*    top4   = (uint4*)(ws + 180480);         // 2 MB
    unsigned short* xh_g = (unsigned short*)(ws + 2277632);    // 8 MB
    unsigned short* xl_g = (unsigned short*)(ws + 10666240);   // 8 MB
    unsigned short* ch_g = (unsigned short*)(ws + 19054848);   // 2 MB
    unsigned short* cl_g = (unsigned short*)(ws + 21152000);   // 2 MB (end ~23.2 MB)

    vq_init_kernel<<<16, 256, 0, stream>>>(colmin, active, accum);
    vq_prep_kernel<<<((N_ROWS + KCODES) * DIM) / 1024, 256, 0, stream>>>(
        x, cb, xh_g, xl_g, ch_g, cl_g);
    vq_sq_np_kernel<<<(N_ROWS + KCODES) / 16, 256, 0, stream>>>(x, cb, xsq, csq);
    vq_gemm_kernel<<<dim3(N_ROWS / TM, NCHUNK), 256, 0, stream>>>(
        xh_g, xl_g, ch_g, cl_g, xsq, csq, colmin, top4);
    vq_refine_kernel<<<N_ROWS / 4, 256, 0, stream>>>(x, cb, top4, tokens, active);
    vq_out_kernel<<<N_ROWS / 4, 256, 0, stream>>>(x, cb, tokens, out, accum);
    vq_final_kernel<<<1, 256, 0, stream>>>(colmin, active, accum, out);
}

// Round 7
// 373.067 us; speedup vs baseline: 1.6938x; 1.0050x over previous
//
#include <hip/hip_runtime.h>
#include <stdint.h>

// ---------------------------------------------------------------------------
// VectorQuantizer: argmin_k ||x_n - c_k||^2 + straight-through out + losses.
//
// Token semantics (R4/R5-verified): generate candidates by continuous score
// s = ||c||^2 - 2 x.c, exact fp64 re-score, token = lowest index within
// 0.75*ulp_fp32(Dmin) of the minimum (matches the reference's fp32 grid /
// tie-to-lowest-index argmin).
//
// R6: 1-term fp16 MFMA GEMM (cross = fl16(x).fl16(c), err std ~6e-4) with a
// widened candidate window: per-chunk top-4 x 8 chunks -> global top-8; the
// refine re-scores all candidates within 3e-3 of the candidate-min in fp64.
// R7 FIX: R6 staged only 8 of each 16-half LDS slice (one uint4 instead of
// two) -> tile columns 8-15/24-31 were stale garbage. Restored the 2x uint4
// per-array staging (R5's proven pattern).
// ---------------------------------------------------------------------------

#define N_ROWS 16384
#define DIM    256
#define KCODES 4096
#define NCHUNK 8
#define KC     (KCODES / NCHUNK)   // 512 codes per chunk
#define TM     128                 // rows per block tile
#define TN     128                 // codes per code-tile
#define BK     32                  // K per staging step
#define NKT    (KC / TN)           // 4 code tiles per chunk
#define NDC    (DIM / BK)          // 8 K-steps
#define LROW   40                  // LDS row stride in halfs (80 B)
#define MSTR   17                  // mrg row stride in uint4 (conflict-free)

typedef float    f32x4 __attribute__((ext_vector_type(4)));
typedef _Float16 f16x8 __attribute__((ext_vector_type(8)));

// order-preserving float->uint key for atomicMin
__device__ __forceinline__ unsigned fkey(float f) {
    unsigned b = __float_as_uint(f);
    return (b & 0x80000000u) ? ~b : (b | 0x80000000u);
}
__device__ __forceinline__ float fkey_inv(unsigned k) {
    unsigned b = (k & 0x80000000u) ? (k ^ 0x80000000u) : ~k;
    return __uint_as_float(b);
}
__device__ __forceinline__ unsigned short f2h(float f) {
    union { _Float16 h; unsigned short u; } cv;
    cv.h = (_Float16)f;            // v_cvt_f16_f32, RNE
    return cv.u;
}

// sorted top-4 insert by (value, index) lexicographic
__device__ __forceinline__ void ins4(float w, int j, float v[4], int id[4]) {
    if (w < v[3] || (w == v[3] && j < id[3])) {
        v[3] = w; id[3] = j;
#pragma unroll
        for (int k = 3; k > 0; --k) {
            if (v[k] < v[k-1] || (v[k] == v[k-1] && id[k] < id[k-1])) {
                float tv = v[k]; v[k] = v[k-1]; v[k-1] = tv;
                int ti = id[k]; id[k] = id[k-1]; id[k-1] = ti;
            }
        }
    }
}
// sorted top-8 insert
__device__ __forceinline__ void ins8(float w, int j, float v[8], int id[8]) {
    if (w < v[7] || (w == v[7] && j < id[7])) {
        v[7] = w; id[7] = j;
#pragma unroll
        for (int k = 7; k > 0; --k) {
            if (v[k] < v[k-1] || (v[k] == v[k-1] && id[k] < id[k-1])) {
                float tv = v[k]; v[k] = v[k-1]; v[k-1] = tv;
                int ti = id[k]; id[k] = id[k-1]; id[k-1] = ti;
            }
        }
    }
}

// ---- prep: fp16 cast + row sumsq (fp64->fp32) + buffer init, fused ----
__global__ __launch_bounds__(256) void vq_prep_kernel(
        const float* __restrict__ x, const float* __restrict__ cb,
        unsigned short* __restrict__ xh, unsigned short* __restrict__ ch,
        float* __restrict__ xsq, float* __restrict__ csq,
        unsigned* __restrict__ colmin_g, unsigned* __restrict__ active,
        double* __restrict__ accum) {
    const int b = blockIdx.x, t = threadIdx.x;
    if (b < KCODES / 256) {
        int i = b * 256 + t;
        colmin_g[i] = 0xFFFFFFFFu; active[i] = 0u;
        if (i == 0) accum[0] = 0.0;
    }
    const size_t NX = (size_t)N_ROWS * DIM;
    size_t e = (size_t)b * 1024 + (size_t)t * 4;
    const float* src; unsigned short* dst; float* sq; size_t off;
    if (e < NX) { src = x;  dst = xh; sq = xsq; off = e; }
    else        { src = cb; dst = ch; sq = csq; off = e - NX; }
    float4 v = *(const float4*)(src + off);
    ushort4 h;
    h.x = f2h(v.x); h.y = f2h(v.y); h.z = f2h(v.z); h.w = f2h(v.w);
    *(ushort4*)(dst + off) = h;
    double s = (double)v.x * v.x + (double)v.y * v.y
             + (double)v.z * v.z + (double)v.w * v.w;
    for (int o = 32; o; o >>= 1) s += __shfl_down(s, o);
    if ((t & 63) == 0) sq[off >> 8] = (float)s;
}

// ---- MFMA candidate GEMM. grid = (N_ROWS/TM, NCHUNK), 256 thr (4 waves 2x2).
__global__ __launch_bounds__(256, 3) void vq_gemm_kernel(
        const unsigned short* __restrict__ xh_g, const unsigned short* __restrict__ ch_g,
        const float* __restrict__ xsq, const float* __restrict__ csq,
        unsigned* __restrict__ colmin_g, uint4* __restrict__ top4_out) {
    __shared__ __align__(16) char smem_raw[MSTR * 128 * 16];   // 34816 B
    __shared__ float    xsq_l[128];
    __shared__ unsigned colmin_l[128];
    unsigned short* xt = (unsigned short*)smem_raw;            // [128][LROW]
    unsigned short* ct = xt + 128 * LROW;
    uint4* mrg = (uint4*)smem_raw;                             // [128][MSTR], aliased

    const int t = threadIdx.x;
    const int wave = t >> 6, lane = t & 63, quad = lane >> 4, L = lane & 15;
    const int whalf = wave >> 1, chalf = wave & 1;
    const int row0  = blockIdx.x * TM;
    const int code0 = blockIdx.y * KC;

    if (t < 128) { xsq_l[t] = xsq[row0 + t]; colmin_l[t] = 0xFFFFFFFFu; }
    __syncthreads();
    float xsqr[16];
#pragma unroll
    for (int mt = 0; mt < 4; ++mt)
#pragma unroll
        for (int r = 0; r < 4; ++r)
            xsqr[mt * 4 + r] = xsq_l[whalf * 64 + mt * 16 + quad * 4 + r];

    const int sr = t >> 1, sh = t & 1;
    const size_t xbase = (size_t)(row0 + sr) * DIM + sh * 16;
    const int so = sr * LROW + sh * 16;

    float vtop[4]; int itop[4];
#pragma unroll
    for (int k = 0; k < 4; ++k) { vtop[k] = 3.4e38f; itop[k] = 0x7FFFFFFF; }

    for (int kt = 0; kt < NKT; ++kt) {
        const int cb0 = code0 + kt * TN;
        const size_t cbase = (size_t)(cb0 + sr) * DIM + sh * 16;
        f32x4 acc[4][4];
#pragma unroll
        for (int mt = 0; mt < 4; ++mt)
#pragma unroll
            for (int nt = 0; nt < 4; ++nt) acc[mt][nt] = (f32x4){0.f, 0.f, 0.f, 0.f};

        for (int dc = 0; dc < NDC; ++dc) {
            __syncthreads();   // protects prior reads of xt/ct AND mrg consumers
            const size_t xo = xbase + dc * BK;
            const size_t co = cbase + dc * BK;
            // 16 halfs per thread per array: two uint4 each (R7 fix)
            uint4 a0 = *(const uint4*)(xh_g + xo);
            uint4 a1 = *(const uint4*)(xh_g + xo + 8);
            uint4 c0 = *(const uint4*)(ch_g + co);
            uint4 c1 = *(const uint4*)(ch_g + co + 8);
            *(uint4*)(xt + so) = a0; *(uint4*)(xt + so + 8) = a1;
            *(uint4*)(ct + so) = c0; *(uint4*)(ct + so + 8) = c1;
            __syncthreads();
            f16x8 af[4], bf[4];
#pragma unroll
            for (int mt = 0; mt < 4; ++mt)
                af[mt] = *(const f16x8*)(xt + (whalf * 64 + mt * 16 + L) * LROW + quad * 8);
#pragma unroll
            for (int nt = 0; nt < 4; ++nt)
                bf[nt] = *(const f16x8*)(ct + (chalf * 64 + nt * 16 + L) * LROW + quad * 8);
#pragma unroll
            for (int mt = 0; mt < 4; ++mt)
#pragma unroll
                for (int nt = 0; nt < 4; ++nt)
                    acc[mt][nt] = __builtin_amdgcn_mfma_f32_16x16x32_f16(
                        af[mt], bf[nt], acc[mt][nt], 0, 0, 0);
        }

        // ---- epilogue: s = csq - 2*cross; top-2/8-code-cell; column-min ----
        __syncthreads();   // all tile reads done -> mrg aliasing safe
        float csq4[4]; int code4[4];
#pragma unroll
        for (int nt = 0; nt < 4; ++nt) {
            code4[nt] = cb0 + chalf * 64 + nt * 16 + L;
            csq4[nt]  = csq[code4[nt]];
        }
        float cmin[4] = {3.4e38f, 3.4e38f, 3.4e38f, 3.4e38f};
#pragma unroll
        for (int mt = 0; mt < 4; ++mt) {
#pragma unroll
            for (int reg = 0; reg < 4; ++reg) {
                float v1 = 3.4e38f, v2 = 3.4e38f;
                int   i1 = 0x7FFFFFFF, i2 = 0x7FFFFFFF;
#pragma unroll
                for (int nt = 0; nt < 4; ++nt) {
                    float s = fmaf(-2.0f, acc[mt][nt][reg], csq4[nt]);
                    if (s < v1)      { v2 = v1; i2 = i1; v1 = s; i1 = code4[nt]; }
                    else if (s < v2) { v2 = s; i2 = code4[nt]; }
                    cmin[nt] = fminf(cmin[nt], xsqr[mt * 4 + reg] + s);
                }
                float w1 = __shfl_xor(v1, 1), w2 = __shfl_xor(v2, 1);
                int   j1 = __shfl_xor(i1, 1), j2 = __shfl_xor(i2, 1);
                if (w1 < v1 || (w1 == v1 && j1 < i1)) { v2 = v1; i2 = i1; v1 = w1; i1 = j1; }
                else if (w1 < v2 || (w1 == v2 && j1 < i2)) { v2 = w1; i2 = j1; }
                if (w2 < v1 || (w2 == v1 && j2 < i1)) { v2 = v1; i2 = i1; v1 = w2; i1 = j2; }
                else if (w2 < v2 || (w2 == v2 && j2 < i2)) { v2 = w2; i2 = j2; }
                if ((L & 1) == 0) {
                    const int rowl = whalf * 64 + mt * 16 + quad * 4 + reg;
                    mrg[rowl * MSTR + chalf * 8 + (L >> 1)] =
                        make_uint4(__float_as_uint(v1), (unsigned)i1,
                                   __float_as_uint(v2), (unsigned)i2);
                }
            }
        }
#pragma unroll
        for (int nt = 0; nt < 4; ++nt)
            atomicMin(&colmin_l[chalf * 64 + nt * 16 + L], fkey(cmin[nt]));
        __syncthreads();
        if (t < 128) {
#pragma unroll
            for (int j = 0; j < 16; ++j) {
                uint4 e = mrg[t * MSTR + j];
                ins4(__uint_as_float(e.x), (int)e.y, vtop, itop);
                ins4(__uint_as_float(e.z), (int)e.w, vtop, itop);
            }
            atomicMin(&colmin_g[cb0 + t], colmin_l[t]);
            colmin_l[t] = 0xFFFFFFFFu;
        }
        // next kt's first dc-step barrier protects mrg/colmin_l reuse
    }

    if (t < 128) {
        size_t base = ((size_t)blockIdx.y * N_ROWS + row0 + t) * 2;
        top4_out[base + 0] = make_uint4(__float_as_uint(vtop[0]), (unsigned)itop[0],
                                        __float_as_uint(vtop[1]), (unsigned)itop[1]);
        top4_out[base + 1] = make_uint4(__float_as_uint(vtop[2]), (unsigned)itop[2],
                                        __float_as_uint(vtop[3]), (unsigned)itop[3]);
    }
}

// ---- refine + gather + MSE, fused. grid = N_ROWS/4, 1 wave per row. ----
__global__ __launch_bounds__(256) void vq_refine_kernel(
        const float* __restrict__ x, const float* __restrict__ cb,
        const uint4* __restrict__ top4, unsigned* __restrict__ active,
        float* __restrict__ out, double* __restrict__ accum) {
    __shared__ double wsum[4];
    const int wave = threadIdx.x >> 6, lane = threadIdx.x & 63;
    const int row  = blockIdx.x * 4 + wave;

    float v[8]; int id[8];
#pragma unroll
    for (int k = 0; k < 8; ++k) { v[k] = 3.4e38f; id[k] = 0x7FFFFFFF; }
#pragma unroll
    for (int c = 0; c < NCHUNK; ++c) {
#pragma unroll
        for (int hh = 0; hh < 2; ++hh) {
            uint4 e = top4[((size_t)c * N_ROWS + row) * 2 + hh];
            ins8(__uint_as_float(e.x), (int)e.y, v, id);
            ins8(__uint_as_float(e.z), (int)e.w, v, id);
        }
    }
    int nq = 1;                               // v sorted ascending; v[0] always
    while (nq < 8 && v[nq] <= v[0] + 3.0e-3f) ++nq;

    float4 xv = ((const float4*)(x + (size_t)row * DIM))[lane];
    double xs64 = (double)xv.x * xv.x + (double)xv.y * xv.y
                + (double)xv.z * xv.z + (double)xv.w * xv.w;
    double dd[8], cc2[8];
    float4 cv[8];
    for (int k = 0; k < nq; ++k) {
        float4 c4 = ((const float4*)(cb + (size_t)id[k] * DIM))[lane];
        cv[k]  = c4;
        dd[k]  = (double)xv.x * c4.x + (double)xv.y * c4.y
               + (double)xv.z * c4.z + (double)xv.w * c4.w;
        cc2[k] = (double)c4.x * c4.x + (double)c4.y * c4.y
               + (double)c4.z * c4.z + (double)c4.w * c4.w;
    }
    for (int o = 32; o; o >>= 1) {
        xs64 += __shfl_down(xs64, o);
        for (int k = 0; k < nq; ++k) {
            dd[k]  += __shfl_down(dd[k], o);
            cc2[k] += __shfl_down(cc2[k], o);
        }
    }
    int wk = 0;
    if (lane == 0) {
        double D[8], Dmin = 1e300;
        for (int k = 0; k < nq; ++k) {
            D[k] = xs64 + cc2[k] - 2.0 * dd[k];
            Dmin = fmin(Dmin, D[k]);
        }
        int e2; frexp(Dmin, &e2);
        double U   = ldexp(1.0, e2 - 1 - 23);     // ulp_fp32(Dmin)
        double thr = Dmin + 0.75 * U;
        int tok = 0x7FFFFFFF;
        for (int k = 0; k < nq; ++k)
            if (D[k] <= thr && id[k] < tok) { tok = id[k]; wk = k; }
        active[tok] = 1u;
    }
    wk = __shfl(wk, 0);
    float4 sel = cv[0];
#pragma unroll
    for (int k = 1; k < 8; ++k) if (k == wk) sel = cv[k];
    ((float4*)out)[(size_t)row * 64 + lane] = sel;
    float dx = sel.x - xv.x, dy = sel.y - xv.y, dz = sel.z - xv.z, dw = sel.w - xv.w;
    float s = dx * dx + dy * dy + dz * dz + dw * dw;
    for (int o = 32; o; o >>= 1) s += __shfl_down(s, o);
    if (lane == 0) wsum[wave] = (double)s;
    __syncthreads();
    if (threadIdx.x == 0) atomicAdd(accum, wsum[0] + wsum[1] + wsum[2] + wsum[3]);
}

// ---- entropy term over inactive classes + final scalar loss ----
__global__ __launch_bounds__(256) void vq_final_kernel(
        const unsigned* __restrict__ colmin_g, const unsigned* __restrict__ active,
        const double* __restrict__ accum, float* __restrict__ out) {
    __shared__ double red[256];
    double s = 0.0;
    for (int k = threadIdx.x; k < KCODES; k += 256)
        if (active[k] == 0u) s += (double)fkey_inv(colmin_g[k]);
    red[threadIdx.x] = s;
    __syncthreads();
    for (int o = 128; o; o >>= 1) {
        if (threadIdx.x < o) red[threadIdx.x] += red[threadIdx.x + o];
        __syncthreads();
    }
    if (threadIdx.x == 0) {
        double loss = 1.25 * (accum[0] / (double)((size_t)N_ROWS * DIM))
                    + 0.02 * (red[0] / (double)KCODES);
        out[(size_t)N_ROWS * DIM] = (float)loss;
    }
}

extern "C" void kernel_launch(void* const* d_in, const int* in_sizes, int n_in,
                              void* d_out, int out_size, void* d_ws, size_t ws_size,
                              hipStream_t stream) {
    const float* x  = (const float*)d_in[0];   // [16384, 256]
    const float* cb = (const float*)d_in[1];   // [4096, 256]
    float* out = (float*)d_out;                // [16384*256] ++ [1] loss

    char* ws = (char*)d_ws;
    float*    xsq    = (float*)(ws + 0);                       // 64 KB
    float*    csq    = (float*)(ws + 65536);                   // 16 KB
    unsigned* colmin = (unsigned*)(ws + 81920);                // 16 KB
    unsigned* active = (unsigned*)(ws + 98304);                // 16 KB
    double*   accum  = (double*)(ws + 114688);                 // 256 B
    uint4*    top4   = (uint4*)(ws + 131072);                  // 4 MB
    unsigned short* xh_g = (unsigned short*)(ws + 4325376);    // 8 MB
    unsigned short* ch_g = (unsigned short*)(ws + 12713984);   // 2 MB (~14.7 MB)

    vq_prep_kernel<<<((N_ROWS + KCODES) * DIM) / 1024, 256, 0, stream>>>(
        x, cb, xh_g, ch_g, xsq, csq, colmin, active, accum);
    vq_gemm_kernel<<<dim3(N_ROWS / TM, NCHUNK), 256, 0, stream>>>(
        xh_g, ch_g, xsq, csq, colmin, top4);
    vq_refine_kernel<<<N_ROWS / 4, 256, 0, stream>>>(
        x, cb, top4, active, out, accum);
    vq_final_kernel<<<1, 256, 0, stream>>>(colmin, active, accum, out);
}

// Round 8
// 371.985 us; speedup vs baseline: 1.6987x; 1.0029x over previous
//
#include <hip/hip_runtime.h>
#include <stdint.h>

// ---------------------------------------------------------------------------
// VectorQuantizer: argmin_k ||x_n - c_k||^2 + straight-through out + losses.
//
// Token semantics (R4/R5/R7-verified): candidates by continuous score
// s = ||c||^2 - 2 x.c via fp16 MFMA (err std ~6e-4), per-chunk top-4 x 8
// chunks -> global top-8; fp64 re-score of all candidates within 3e-3 of the
// candidate-min; token = lowest index within 0.75*ulp_fp32(Dmin).
//
// R8: the R7 K-loop was barrier/latency-bound (time ~ staging iterations;
// MfmaUtil 7%, VALUBusy 28%, HBM 10% -- all idle). New K-loop loads A/B MFMA
// fragments DIRECTLY from global (dwordx4/lane, same fragment elements as the
// LDS path -> identical acc bits), no __syncthreads in the K-loop at all;
// LDS is only the per-kt epilogue merge (8 barriers/block vs 72).
// ---------------------------------------------------------------------------

#define N_ROWS 16384
#define DIM    256
#define KCODES 4096
#define NCHUNK 8
#define KC     (KCODES / NCHUNK)   // 512 codes per chunk
#define TM     128                 // rows per block tile
#define TN     128                 // codes per code-tile
#define BK     32                  // K per dc step
#define NKT    (KC / TN)           // 4 code tiles per chunk
#define NDC    (DIM / BK)          // 8 K-steps
#define MSTR   17                  // mrg row stride in uint4 (conflict-free)

typedef float    f32x4 __attribute__((ext_vector_type(4)));
typedef _Float16 f16x8 __attribute__((ext_vector_type(8)));

// order-preserving float->uint key for atomicMin
__device__ __forceinline__ unsigned fkey(float f) {
    unsigned b = __float_as_uint(f);
    return (b & 0x80000000u) ? ~b : (b | 0x80000000u);
}
__device__ __forceinline__ float fkey_inv(unsigned k) {
    unsigned b = (k & 0x80000000u) ? (k ^ 0x80000000u) : ~k;
    return __uint_as_float(b);
}
__device__ __forceinline__ unsigned short f2h(float f) {
    union { _Float16 h; unsigned short u; } cv;
    cv.h = (_Float16)f;            // v_cvt_f16_f32, RNE
    return cv.u;
}

// sorted top-4 insert by (value, index) lexicographic
__device__ __forceinline__ void ins4(float w, int j, float v[4], int id[4]) {
    if (w < v[3] || (w == v[3] && j < id[3])) {
        v[3] = w; id[3] = j;
#pragma unroll
        for (int k = 3; k > 0; --k) {
            if (v[k] < v[k-1] || (v[k] == v[k-1] && id[k] < id[k-1])) {
                float tv = v[k]; v[k] = v[k-1]; v[k-1] = tv;
                int ti = id[k]; id[k] = id[k-1]; id[k-1] = ti;
            }
        }
    }
}
// sorted top-8 insert
__device__ __forceinline__ void ins8(float w, int j, float v[8], int id[8]) {
    if (w < v[7] || (w == v[7] && j < id[7])) {
        v[7] = w; id[7] = j;
#pragma unroll
        for (int k = 7; k > 0; --k) {
            if (v[k] < v[k-1] || (v[k] == v[k-1] && id[k] < id[k-1])) {
                float tv = v[k]; v[k] = v[k-1]; v[k-1] = tv;
                int ti = id[k]; id[k] = id[k-1]; id[k-1] = ti;
            }
        }
    }
}

// ---- prep: fp16 cast + row sumsq (fp64->fp32) + buffer init, fused ----
__global__ __launch_bounds__(256) void vq_prep_kernel(
        const float* __restrict__ x, const float* __restrict__ cb,
        unsigned short* __restrict__ xh, unsigned short* __restrict__ ch,
        float* __restrict__ xsq, float* __restrict__ csq,
        unsigned* __restrict__ colmin_g, unsigned* __restrict__ active,
        double* __restrict__ accum) {
    const int b = blockIdx.x, t = threadIdx.x;
    if (b < KCODES / 256) {
        int i = b * 256 + t;
        colmin_g[i] = 0xFFFFFFFFu; active[i] = 0u;
        if (i == 0) accum[0] = 0.0;
    }
    const size_t NX = (size_t)N_ROWS * DIM;
    size_t e = (size_t)b * 1024 + (size_t)t * 4;
    const float* src; unsigned short* dst; float* sq; size_t off;
    if (e < NX) { src = x;  dst = xh; sq = xsq; off = e; }
    else        { src = cb; dst = ch; sq = csq; off = e - NX; }
    float4 v = *(const float4*)(src + off);
    ushort4 h;
    h.x = f2h(v.x); h.y = f2h(v.y); h.z = f2h(v.z); h.w = f2h(v.w);
    *(ushort4*)(dst + off) = h;
    double s = (double)v.x * v.x + (double)v.y * v.y
             + (double)v.z * v.z + (double)v.w * v.w;
    for (int o = 32; o; o >>= 1) s += __shfl_down(s, o);
    if ((t & 63) == 0) sq[off >> 8] = (float)s;
}

// ---- MFMA candidate GEMM, barrier-free K-loop.
// grid = (N_ROWS/TM, NCHUNK), 256 thr (4 waves, 2x2 of 64x64).
__global__ __launch_bounds__(256, 2) void vq_gemm_kernel(
        const unsigned short* __restrict__ xh_g, const unsigned short* __restrict__ ch_g,
        const float* __restrict__ xsq, const float* __restrict__ csq,
        unsigned* __restrict__ colmin_g, uint4* __restrict__ top4_out) {
    __shared__ __align__(16) uint4 mrg[128 * MSTR];   // 34816 B, epilogue only
    __shared__ float    xsq_l[128];
    __shared__ unsigned colmin_l[128];

    const int t = threadIdx.x;
    const int wave = t >> 6, lane = t & 63, quad = lane >> 4, L = lane & 15;
    const int whalf = wave >> 1, chalf = wave & 1;
    const int row0  = blockIdx.x * TM;
    const int code0 = blockIdx.y * KC;

    if (t < 128) { xsq_l[t] = xsq[row0 + t]; colmin_l[t] = 0xFFFFFFFFu; }
    __syncthreads();
    float xsqr[16];
#pragma unroll
    for (int mt = 0; mt < 4; ++mt)
#pragma unroll
        for (int r = 0; r < 4; ++r)
            xsqr[mt * 4 + r] = xsq_l[whalf * 64 + mt * 16 + quad * 4 + r];

    // A-fragment base: row = row0 + whalf*64 + mt*16 + L, k-offset quad*8
    const unsigned short* abase =
        xh_g + ((size_t)(row0 + whalf * 64 + L) * DIM + quad * 8);

    float vtop[4]; int itop[4];
#pragma unroll
    for (int k = 0; k < 4; ++k) { vtop[k] = 3.4e38f; itop[k] = 0x7FFFFFFF; }

    for (int kt = 0; kt < NKT; ++kt) {
        const int cb0 = code0 + kt * TN;
        const unsigned short* bbase =
            ch_g + ((size_t)(cb0 + chalf * 64 + L) * DIM + quad * 8);
        f32x4 acc[4][4];
#pragma unroll
        for (int mt = 0; mt < 4; ++mt)
#pragma unroll
            for (int nt = 0; nt < 4; ++nt) acc[mt][nt] = (f32x4){0.f, 0.f, 0.f, 0.f};

        __syncthreads();   // mrg/colmin_l from previous kt fully consumed

        // ---- barrier-free K-loop: direct-global fragments + MFMA ----
#pragma unroll
        for (int dc = 0; dc < NDC; ++dc) {
            f16x8 af[4], bf[4];
#pragma unroll
            for (int mt = 0; mt < 4; ++mt)
                af[mt] = *(const f16x8*)(abase + (size_t)mt * 16 * DIM + dc * BK);
#pragma unroll
            for (int nt = 0; nt < 4; ++nt)
                bf[nt] = *(const f16x8*)(bbase + (size_t)nt * 16 * DIM + dc * BK);
#pragma unroll
            for (int mt = 0; mt < 4; ++mt)
#pragma unroll
                for (int nt = 0; nt < 4; ++nt)
                    acc[mt][nt] = __builtin_amdgcn_mfma_f32_16x16x32_f16(
                        af[mt], bf[nt], acc[mt][nt], 0, 0, 0);
        }

        // ---- epilogue: s = csq - 2*cross; top-2/8-code-cell; column-min ----
        float csq4[4]; int code4[4];
#pragma unroll
        for (int nt = 0; nt < 4; ++nt) {
            code4[nt] = cb0 + chalf * 64 + nt * 16 + L;
            csq4[nt]  = csq[code4[nt]];
        }
        float cmin[4] = {3.4e38f, 3.4e38f, 3.4e38f, 3.4e38f};
#pragma unroll
        for (int mt = 0; mt < 4; ++mt) {
#pragma unroll
            for (int reg = 0; reg < 4; ++reg) {
                float v1 = 3.4e38f, v2 = 3.4e38f;
                int   i1 = 0x7FFFFFFF, i2 = 0x7FFFFFFF;
#pragma unroll
                for (int nt = 0; nt < 4; ++nt) {
                    float s = fmaf(-2.0f, acc[mt][nt][reg], csq4[nt]);
                    if (s < v1)      { v2 = v1; i2 = i1; v1 = s; i1 = code4[nt]; }
                    else if (s < v2) { v2 = s; i2 = code4[nt]; }
                    cmin[nt] = fminf(cmin[nt], xsqr[mt * 4 + reg] + s);
                }
                float w1 = __shfl_xor(v1, 1), w2 = __shfl_xor(v2, 1);
                int   j1 = __shfl_xor(i1, 1), j2 = __shfl_xor(i2, 1);
                if (w1 < v1 || (w1 == v1 && j1 < i1)) { v2 = v1; i2 = i1; v1 = w1; i1 = j1; }
                else if (w1 < v2 || (w1 == v2 && j1 < i2)) { v2 = w1; i2 = j1; }
                if (w2 < v1 || (w2 == v1 && j2 < i1)) { v2 = v1; i2 = i1; v1 = w2; i1 = j2; }
                else if (w2 < v2 || (w2 == v2 && j2 < i2)) { v2 = w2; i2 = j2; }
                if ((L & 1) == 0) {
                    const int rowl = whalf * 64 + mt * 16 + quad * 4 + reg;
                    mrg[rowl * MSTR + chalf * 8 + (L >> 1)] =
                        make_uint4(__float_as_uint(v1), (unsigned)i1,
                                   __float_as_uint(v2), (unsigned)i2);
                }
            }
        }
#pragma unroll
        for (int nt = 0; nt < 4; ++nt)
            atomicMin(&colmin_l[chalf * 64 + nt * 16 + L], fkey(cmin[nt]));
        __syncthreads();
        if (t < 128) {
#pragma unroll
            for (int j = 0; j < 16; ++j) {
                uint4 e = mrg[t * MSTR + j];
                ins4(__uint_as_float(e.x), (int)e.y, vtop, itop);
                ins4(__uint_as_float(e.z), (int)e.w, vtop, itop);
            }
            atomicMin(&colmin_g[cb0 + t], colmin_l[t]);
            colmin_l[t] = 0xFFFFFFFFu;
        }
        // next kt's top barrier protects mrg/colmin_l reuse
    }

    if (t < 128) {
        size_t base = ((size_t)blockIdx.y * N_ROWS + row0 + t) * 2;
        top4_out[base + 0] = make_uint4(__float_as_uint(vtop[0]), (unsigned)itop[0],
                                        __float_as_uint(vtop[1]), (unsigned)itop[1]);
        top4_out[base + 1] = make_uint4(__float_as_uint(vtop[2]), (unsigned)itop[2],
                                        __float_as_uint(vtop[3]), (unsigned)itop[3]);
    }
}

// ---- refine + gather + MSE, fused. grid = N_ROWS/4, 1 wave per row. ----
__global__ __launch_bounds__(256) void vq_refine_kernel(
        const float* __restrict__ x, const float* __restrict__ cb,
        const uint4* __restrict__ top4, unsigned* __restrict__ active,
        float* __restrict__ out, double* __restrict__ accum) {
    __shared__ double wsum[4];
    const int wave = threadIdx.x >> 6, lane = threadIdx.x & 63;
    const int row  = blockIdx.x * 4 + wave;

    float v[8]; int id[8];
#pragma unroll
    for (int k = 0; k < 8; ++k) { v[k] = 3.4e38f; id[k] = 0x7FFFFFFF; }
#pragma unroll
    for (int c = 0; c < NCHUNK; ++c) {
#pragma unroll
        for (int hh = 0; hh < 2; ++hh) {
            uint4 e = top4[((size_t)c * N_ROWS + row) * 2 + hh];
            ins8(__uint_as_float(e.x), (int)e.y, v, id);
            ins8(__uint_as_float(e.z), (int)e.w, v, id);
        }
    }
    int nq = 1;                               // v sorted ascending; v[0] always
    while (nq < 8 && v[nq] <= v[0] + 3.0e-3f) ++nq;

    float4 xv = ((const float4*)(x + (size_t)row * DIM))[lane];
    double xs64 = (double)xv.x * xv.x + (double)xv.y * xv.y
                + (double)xv.z * xv.z + (double)xv.w * xv.w;
    double dd[8], cc2[8];
    float4 cv[8];
    for (int k = 0; k < nq; ++k) {
        float4 c4 = ((const float4*)(cb + (size_t)id[k] * DIM))[lane];
        cv[k]  = c4;
        dd[k]  = (double)xv.x * c4.x + (double)xv.y * c4.y
               + (double)xv.z * c4.z + (double)xv.w * c4.w;
        cc2[k] = (double)c4.x * c4.x + (double)c4.y * c4.y
               + (double)c4.z * c4.z + (double)c4.w * c4.w;
    }
    for (int o = 32; o; o >>= 1) {
        xs64 += __shfl_down(xs64, o);
        for (int k = 0; k < nq; ++k) {
            dd[k]  += __shfl_down(dd[k], o);
            cc2[k] += __shfl_down(cc2[k], o);
        }
    }
    int wk = 0;
    if (lane == 0) {
        double D[8], Dmin = 1e300;
        for (int k = 0; k < nq; ++k) {
            D[k] = xs64 + cc2[k] - 2.0 * dd[k];
            Dmin = fmin(Dmin, D[k]);
        }
        int e2; frexp(Dmin, &e2);
        double U   = ldexp(1.0, e2 - 1 - 23);     // ulp_fp32(Dmin)
        double thr = Dmin + 0.75 * U;
        int tok = 0x7FFFFFFF;
        for (int k = 0; k < nq; ++k)
            if (D[k] <= thr && id[k] < tok) { tok = id[k]; wk = k; }
        active[tok] = 1u;
    }
    wk = __shfl(wk, 0);
    float4 sel = cv[0];
#pragma unroll
    for (int k = 1; k < 8; ++k) if (k == wk) sel = cv[k];
    ((float4*)out)[(size_t)row * 64 + lane] = sel;
    float dx = sel.x - xv.x, dy = sel.y - xv.y, dz = sel.z - xv.z, dw = sel.w - xv.w;
    float s = dx * dx + dy * dy + dz * dz + dw * dw;
    for (int o = 32; o; o >>= 1) s += __shfl_down(s, o);
    if (lane == 0) wsum[wave] = (double)s;
    __syncthreads();
    if (threadIdx.x == 0) atomicAdd(accum, wsum[0] + wsum[1] + wsum[2] + wsum[3]);
}

// ---- entropy term over inactive classes + final scalar loss ----
__global__ __launch_bounds__(256) void vq_final_kernel(
        const unsigned* __restrict__ colmin_g, const unsigned* __restrict__ active,
        const double* __restrict__ accum, float* __restrict__ out) {
    __shared__ double red[256];
    double s = 0.0;
    for (int k = threadIdx.x; k < KCODES; k += 256)
        if (active[k] == 0u) s += (double)fkey_inv(colmin_g[k]);
    red[threadIdx.x] = s;
    __syncthreads();
    for (int o = 128; o; o >>= 1) {
        if (threadIdx.x < o) red[threadIdx.x] += red[threadIdx.x + o];
        __syncthreads();
    }
    if (threadIdx.x == 0) {
        double loss = 1.25 * (accum[0] / (double)((size_t)N_ROWS * DIM))
                    + 0.02 * (red[0] / (double)KCODES);
        out[(size_t)N_ROWS * DIM] = (float)loss;
    }
}

extern "C" void kernel_launch(void* const* d_in, const int* in_sizes, int n_in,
                              void* d_out, int out_size, void* d_ws, size_t ws_size,
                              hipStream_t stream) {
    const float* x  = (const float*)d_in[0];   // [16384, 256]
    const float* cb = (const float*)d_in[1];   // [4096, 256]
    float* out = (float*)d_out;                // [16384*256] ++ [1] loss

    char* ws = (char*)d_ws;
    float*    xsq    = (float*)(ws + 0);                       // 64 KB
    float*    csq    = (float*)(ws + 65536);                   // 16 KB
    unsigned* colmin = (unsigned*)(ws + 81920);                // 16 KB
    unsigned* active = (unsigned*)(ws + 98304);                // 16 KB
    double*   accum  = (double*)(ws + 114688);                 // 256 B
    uint4*    top4   = (uint4*)(ws + 131072);                  // 4 MB
    unsigned short* xh_g = (unsigned short*)(ws + 4325376);    // 8 MB
    unsigned short* ch_g = (unsigned short*)(ws + 12713984);   // 2 MB (~14.7 MB)

    vq_prep_kernel<<<((N_ROWS + KCODES) * DIM) / 1024, 256, 0, stream>>>(
        x, cb, xh_g, ch_g, xsq, csq, colmin, active, accum);
    vq_gemm_kernel<<<dim3(N_ROWS / TM, NCHUNK), 256, 0, stream>>>(
        xh_g, ch_g, xsq, csq, colmin, top4);
    vq_refine_kernel<<<N_ROWS / 4, 256, 0, stream>>>(
        x, cb, top4, active, out, accum);
    vq_final_kernel<<<1, 256, 0, stream>>>(colmin, active, accum, out);
}

// Round 9
// 309.459 us; speedup vs baseline: 2.0419x; 1.2021x over previous
//
#include <hip/hip_runtime.h>
#include <stdint.h>

// ---------------------------------------------------------------------------
// VectorQuantizer: argmin_k ||x_n - c_k||^2 + straight-through out + losses.
//
// Token semantics (R4/R5/R7-verified): candidates by continuous score
// s = ||c||^2 - 2 x.c via fp16 MFMA; fp64 re-score of all candidates within a
// window of the candidate-min; token = lowest index within 0.75*ulp_fp32(Dmin).
//
// R9: the per-kt epilogue (shfl merges + LDS atomics + divergent ins4 chains)
// was the bottleneck (R5/R7/R8 time ~ #epilogues, not FLOPs/staging). New
// epilogue packs (score,col) into one order-preserving uint key
// (fkey(s) & ~0x1FF | col9); per-score top-2 upkeep = 3 umin/umax VALU ops;
// cross-lane butterfly merge + store happen ONCE per block; column-min via 2
// shuffles + fire-and-forget global atomicMin. Zero K-loop barriers, zero LDS
// (except a 128-float xsq stage). Candidates: top-2 per 256-col granule x 16
// granules -> global top-8, window 3.5e-3 (quantization 2.4e-4 absorbed).
// ---------------------------------------------------------------------------

#define N_ROWS 16384
#define DIM    256
#define KCODES 4096
#define NCHUNK 8
#define KC     (KCODES / NCHUNK)   // 512 codes per chunk
#define TM     128                 // rows per block tile
#define TN     128                 // codes per code-tile
#define BK     32                  // K per dc step
#define NKT    (KC / TN)           // 4 code tiles per chunk
#define NDC    (DIM / BK)          // 8 K-steps
#define NGRAN  (NCHUNK * 2)        // 16 granules of 256 cols (chunk x chalf)

typedef float    f32x4 __attribute__((ext_vector_type(4)));
typedef _Float16 f16x8 __attribute__((ext_vector_type(8)));

__device__ __forceinline__ unsigned umin_(unsigned a, unsigned b) { return a < b ? a : b; }
__device__ __forceinline__ unsigned umax_(unsigned a, unsigned b) { return a > b ? a : b; }

// order-preserving float->uint key
__device__ __forceinline__ unsigned fkey(float f) {
    unsigned b = __float_as_uint(f);
    return (b & 0x80000000u) ? ~b : (b | 0x80000000u);
}
__device__ __forceinline__ float fkey_inv(unsigned k) {
    unsigned b = (k & 0x80000000u) ? (k ^ 0x80000000u) : ~k;
    return __uint_as_float(b);
}
__device__ __forceinline__ unsigned short f2h(float f) {
    union { _Float16 h; unsigned short u; } cv;
    cv.h = (_Float16)f;            // v_cvt_f16_f32, RNE
    return cv.u;
}

// sorted top-8 insert by (value, index) lexicographic
__device__ __forceinline__ void ins8(float w, int j, float v[8], int id[8]) {
    if (w < v[7] || (w == v[7] && j < id[7])) {
        v[7] = w; id[7] = j;
#pragma unroll
        for (int k = 7; k > 0; --k) {
            if (v[k] < v[k-1] || (v[k] == v[k-1] && id[k] < id[k-1])) {
                float tv = v[k]; v[k] = v[k-1]; v[k-1] = tv;
                int ti = id[k]; id[k] = id[k-1]; id[k-1] = ti;
            }
        }
    }
}

// ---- prep: fp16 cast + row sumsq (fp64->fp32) + buffer init, fused ----
__global__ __launch_bounds__(256) void vq_prep_kernel(
        const float* __restrict__ x, const float* __restrict__ cb,
        unsigned short* __restrict__ xh, unsigned short* __restrict__ ch,
        float* __restrict__ xsq, float* __restrict__ csq,
        unsigned* __restrict__ colmin_g, unsigned* __restrict__ active,
        double* __restrict__ accum) {
    const int b = blockIdx.x, t = threadIdx.x;
    if (b < KCODES / 256) {
        int i = b * 256 + t;
        colmin_g[i] = 0xFFFFFFFFu; active[i] = 0u;
        if (i == 0) accum[0] = 0.0;
    }
    const size_t NX = (size_t)N_ROWS * DIM;
    size_t e = (size_t)b * 1024 + (size_t)t * 4;
    const float* src; unsigned short* dst; float* sq; size_t off;
    if (e < NX) { src = x;  dst = xh; sq = xsq; off = e; }
    else        { src = cb; dst = ch; sq = csq; off = e - NX; }
    float4 v = *(const float4*)(src + off);
    ushort4 h;
    h.x = f2h(v.x); h.y = f2h(v.y); h.z = f2h(v.z); h.w = f2h(v.w);
    *(ushort4*)(dst + off) = h;
    double s = (double)v.x * v.x + (double)v.y * v.y
             + (double)v.z * v.z + (double)v.w * v.w;
    for (int o = 32; o; o >>= 1) s += __shfl_down(s, o);
    if ((t & 63) == 0) sq[off >> 8] = (float)s;
}

// ---- MFMA candidate GEMM, barrier-free, packed-key epilogue.
// grid = (N_ROWS/TM, NCHUNK), 256 thr (4 waves, 2x2 of 64x64).
__global__ __launch_bounds__(256, 2) void vq_gemm_kernel(
        const unsigned short* __restrict__ xh_g, const unsigned short* __restrict__ ch_g,
        const float* __restrict__ xsq, const float* __restrict__ csq,
        unsigned* __restrict__ colmin_g, uint2* __restrict__ top2_out) {
    __shared__ float xsq_l[128];

    const int t = threadIdx.x;
    const int wave = t >> 6, lane = t & 63, quad = lane >> 4, L = lane & 15;
    const int whalf = wave >> 1, chalf = wave & 1;
    const int row0  = blockIdx.x * TM;
    const int code0 = blockIdx.y * KC;

    if (t < 128) xsq_l[t] = xsq[row0 + t];
    __syncthreads();
    float xsqr[16];
#pragma unroll
    for (int mt = 0; mt < 4; ++mt)
#pragma unroll
        for (int r = 0; r < 4; ++r)
            xsqr[mt * 4 + r] = xsq_l[whalf * 64 + mt * 16 + quad * 4 + r];

    const unsigned short* abase =
        xh_g + ((size_t)(row0 + whalf * 64 + L) * DIM + quad * 8);

    unsigned u1[16], u2[16];   // packed (quantized score | col9) running top-2
#pragma unroll
    for (int i = 0; i < 16; ++i) { u1[i] = 0xFFFFFFFFu; u2[i] = 0xFFFFFFFFu; }

    for (int kt = 0; kt < NKT; ++kt) {
        const int cb0 = code0 + kt * TN;
        const unsigned short* bbase =
            ch_g + ((size_t)(cb0 + chalf * 64 + L) * DIM + quad * 8);
        f32x4 acc[4][4];
#pragma unroll
        for (int mt = 0; mt < 4; ++mt)
#pragma unroll
            for (int nt = 0; nt < 4; ++nt) acc[mt][nt] = (f32x4){0.f, 0.f, 0.f, 0.f};

#pragma unroll
        for (int dc = 0; dc < NDC; ++dc) {
            f16x8 af[4], bf[4];
#pragma unroll
            for (int mt = 0; mt < 4; ++mt)
                af[mt] = *(const f16x8*)(abase + (size_t)mt * 16 * DIM + dc * BK);
#pragma unroll
            for (int nt = 0; nt < 4; ++nt)
                bf[nt] = *(const f16x8*)(bbase + (size_t)nt * 16 * DIM + dc * BK);
#pragma unroll
            for (int mt = 0; mt < 4; ++mt)
#pragma unroll
                for (int nt = 0; nt < 4; ++nt)
                    acc[mt][nt] = __builtin_amdgcn_mfma_f32_16x16x32_f16(
                        af[mt], bf[nt], acc[mt][nt], 0, 0, 0);
        }

        // ---- epilogue: packed-key top-2 upkeep + column-min ----
        float csq4[4]; unsigned colf[4];
        float dmin[4] = {3.4e38f, 3.4e38f, 3.4e38f, 3.4e38f};
#pragma unroll
        for (int nt = 0; nt < 4; ++nt) {
            csq4[nt] = csq[cb0 + chalf * 64 + nt * 16 + L];
            colf[nt] = (unsigned)(kt * 128 + chalf * 64 + nt * 16 + L);
        }
#pragma unroll
        for (int mt = 0; mt < 4; ++mt) {
#pragma unroll
            for (int reg = 0; reg < 4; ++reg) {
                const int i = mt * 4 + reg;
#pragma unroll
                for (int nt = 0; nt < 4; ++nt) {
                    float s = fmaf(-2.0f, acc[mt][nt][reg], csq4[nt]);
                    unsigned key = (fkey(s) & 0xFFFFFE00u) | colf[nt];
                    unsigned lo = umin_(u1[i], key);
                    u2[i] = umin_(u2[i], umax_(u1[i], key));
                    u1[i] = lo;
                    dmin[nt] = fminf(dmin[nt], xsqr[i] + s);
                }
            }
        }
#pragma unroll
        for (int nt = 0; nt < 4; ++nt) {
            unsigned dk = fkey(dmin[nt]);
            dk = umin_(dk, (unsigned)__shfl_xor((int)dk, 16));
            dk = umin_(dk, (unsigned)__shfl_xor((int)dk, 32));
            if (quad == 0)
                atomicMin(&colmin_g[cb0 + chalf * 64 + nt * 16 + L], dk);
        }
    }

    // ---- once per block: butterfly-merge top-2 across the 16 L-lanes ----
#pragma unroll
    for (int i = 0; i < 16; ++i) {
#pragma unroll
        for (int st = 1; st < 16; st <<= 1) {
            unsigned w1 = (unsigned)__shfl_xor((int)u1[i], st);
            unsigned w2 = (unsigned)__shfl_xor((int)u2[i], st);
            unsigned a = umin_(u1[i], w1), b = umax_(u1[i], w1);
            u1[i] = a;
            u2[i] = umin_(umin_(u2[i], w2), b);
        }
    }
    if (L == 0) {
        const size_t gbase = (size_t)(blockIdx.y * 2 + chalf) * N_ROWS;
#pragma unroll
        for (int mt = 0; mt < 4; ++mt)
#pragma unroll
            for (int reg = 0; reg < 4; ++reg) {
                const int row = row0 + whalf * 64 + mt * 16 + quad * 4 + reg;
                top2_out[gbase + row] = make_uint2(u1[mt * 4 + reg], u2[mt * 4 + reg]);
            }
    }
}

// ---- refine + gather + MSE, fused. grid = N_ROWS/4, 1 wave per row. ----
// Decode 16 granules' packed top-2 -> top-8 by (value,code); fp64 re-score of
// candidates within 3.5e-3 of the min; token = lowest index within
// 0.75*ulp_fp32(Dmin); write out = cb[token]; accumulate sum((emb-x)^2).
__global__ __launch_bounds__(256) void vq_refine_kernel(
        const float* __restrict__ x, const float* __restrict__ cb,
        const uint2* __restrict__ top2, unsigned* __restrict__ active,
        float* __restrict__ out, double* __restrict__ accum) {
    __shared__ double wsum[4];
    const int wave = threadIdx.x >> 6, lane = threadIdx.x & 63;
    const int row  = blockIdx.x * 4 + wave;

    float v[8]; int id[8];
#pragma unroll
    for (int k = 0; k < 8; ++k) { v[k] = 3.4e38f; id[k] = 0x7FFFFFFF; }
#pragma unroll
    for (int g = 0; g < NGRAN; ++g) {
        uint2 e = top2[(size_t)g * N_ROWS + row];
        const int cbase = (g >> 1) * KC;
        ins8(fkey_inv(e.x & 0xFFFFFE00u), cbase + (int)(e.x & 0x1FFu), v, id);
        ins8(fkey_inv(e.y & 0xFFFFFE00u), cbase + (int)(e.y & 0x1FFu), v, id);
    }
    int nq = 1;                               // v sorted ascending; v[0] always
    while (nq < 8 && v[nq] <= v[0] + 3.5e-3f) ++nq;

    float4 xv = ((const float4*)(x + (size_t)row * DIM))[lane];
    double xs64 = (double)xv.x * xv.x + (double)xv.y * xv.y
                + (double)xv.z * xv.z + (double)xv.w * xv.w;
    double dd[8], cc2[8];
    float4 cv[8];
    for (int k = 0; k < nq; ++k) {
        float4 c4 = ((const float4*)(cb + (size_t)id[k] * DIM))[lane];
        cv[k]  = c4;
        dd[k]  = (double)xv.x * c4.x + (double)xv.y * c4.y
               + (double)xv.z * c4.z + (double)xv.w * c4.w;
        cc2[k] = (double)c4.x * c4.x + (double)c4.y * c4.y
               + (double)c4.z * c4.z + (double)c4.w * c4.w;
    }
    for (int o = 32; o; o >>= 1) {
        xs64 += __shfl_down(xs64, o);
        for (int k = 0; k < nq; ++k) {
            dd[k]  += __shfl_down(dd[k], o);
            cc2[k] += __shfl_down(cc2[k], o);
        }
    }
    int wk = 0;
    if (lane == 0) {
        double D[8], Dmin = 1e300;
        for (int k = 0; k < nq; ++k) {
            D[k] = xs64 + cc2[k] - 2.0 * dd[k];
            Dmin = fmin(Dmin, D[k]);
        }
        int e2; frexp(Dmin, &e2);
        double U   = ldexp(1.0, e2 - 1 - 23);     // ulp_fp32(Dmin)
        double thr = Dmin + 0.75 * U;
        int tok = 0x7FFFFFFF;
        for (int k = 0; k < nq; ++k)
            if (D[k] <= thr && id[k] < tok) { tok = id[k]; wk = k; }
        active[tok] = 1u;
    }
    wk = __shfl(wk, 0);
    float4 sel = cv[0];
#pragma unroll
    for (int k = 1; k < 8; ++k) if (k == wk) sel = cv[k];
    ((float4*)out)[(size_t)row * 64 + lane] = sel;
    float dx = sel.x - xv.x, dy = sel.y - xv.y, dz = sel.z - xv.z, dw = sel.w - xv.w;
    float s = dx * dx + dy * dy + dz * dz + dw * dw;
    for (int o = 32; o; o >>= 1) s += __shfl_down(s, o);
    if (lane == 0) wsum[wave] = (double)s;
    __syncthreads();
    if (threadIdx.x == 0) atomicAdd(accum, wsum[0] + wsum[1] + wsum[2] + wsum[3]);
}

// ---- entropy term over inactive classes + final scalar loss ----
__global__ __launch_bounds__(256) void vq_final_kernel(
        const unsigned* __restrict__ colmin_g, const unsigned* __restrict__ active,
        const double* __restrict__ accum, float* __restrict__ out) {
    __shared__ double red[256];
    double s = 0.0;
    for (int k = threadIdx.x; k < KCODES; k += 256)
        if (active[k] == 0u) s += (double)fkey_inv(colmin_g[k]);
    red[threadIdx.x] = s;
    __syncthreads();
    for (int o = 128; o; o >>= 1) {
        if (threadIdx.x < o) red[threadIdx.x] += red[threadIdx.x + o];
        __syncthreads();
    }
    if (threadIdx.x == 0) {
        double loss = 1.25 * (accum[0] / (double)((size_t)N_ROWS * DIM))
                    + 0.02 * (red[0] / (double)KCODES);
        out[(size_t)N_ROWS * DIM] = (float)loss;
    }
}

extern "C" void kernel_launch(void* const* d_in, const int* in_sizes, int n_in,
                              void* d_out, int out_size, void* d_ws, size_t ws_size,
                              hipStream_t stream) {
    const float* x  = (const float*)d_in[0];   // [16384, 256]
    const float* cb = (const float*)d_in[1];   // [4096, 256]
    float* out = (float*)d_out;                // [16384*256] ++ [1] loss

    char* ws = (char*)d_ws;
    float*    xsq    = (float*)(ws + 0);                       // 64 KB
    float*    csq    = (float*)(ws + 65536);                   // 16 KB
    unsigned* colmin = (unsigned*)(ws + 81920);                // 16 KB
    unsigned* active = (unsigned*)(ws + 98304);                // 16 KB
    double*   accum  = (double*)(ws + 114688);                 // 256 B
    uint2*    top2   = (uint2*)(ws + 131072);                  // 2 MB (16 granules)
    unsigned short* xh_g = (unsigned short*)(ws + 2228224);    // 8 MB
    unsigned short* ch_g = (unsigned short*)(ws + 10616832);   // 2 MB (~12.6 MB)

    vq_prep_kernel<<<((N_ROWS + KCODES) * DIM) / 1024, 256, 0, stream>>>(
        x, cb, xh_g, ch_g, xsq, csq, colmin, active, accum);
    vq_gemm_kernel<<<dim3(N_ROWS / TM, NCHUNK), 256, 0, stream>>>(
        xh_g, ch_g, xsq, csq, colmin, top2);
    vq_refine_kernel<<<N_ROWS / 4, 256, 0, stream>>>(
        x, cb, top2, active, out, accum);
    vq_final_kernel<<<1, 256, 0, stream>>>(colmin, active, accum, out);
}

// Round 10
// 278.811 us; speedup vs baseline: 2.2664x; 1.1099x over previous
//
#include <hip/hip_runtime.h>
#include <stdint.h>

// ---------------------------------------------------------------------------
// VectorQuantizer: argmin_k ||x_n - c_k||^2 + straight-through out + losses.
//
// Token semantics (R4/R5/R7/R9-verified): candidates by continuous score
// s = ||c||^2 - 2 x.c via fp16 MFMA; exact fp64 re-score; token = lowest
// index within 0.75*ulp_fp32(Dmin) of the minimum.
//
// R9: packed-key (score|col) epilogue -> gemm 197->129us (epilogue was the
// bottleneck, confirmed).
// R10: refine rewrite. R8/R9's runtime-bound loops (k<nq) over dd/cc2/cv[]
// forced those arrays to scratch (global-backed) -> hidden ~100us of private
// memory traffic. New refine: uniform fast path (cert. winner if candidate
// gap > 1e-2, ~96% of rows, no fp64) + fixed-bound fully-unrolled slow path
// (all 8 candidates, registers only). GEMM kernel untouched.
// ---------------------------------------------------------------------------

#define N_ROWS 16384
#define DIM    256
#define KCODES 4096
#define NCHUNK 8
#define KC     (KCODES / NCHUNK)   // 512 codes per chunk
#define TM     128                 // rows per block tile
#define TN     128                 // codes per code-tile
#define BK     32                  // K per dc step
#define NKT    (KC / TN)           // 4 code tiles per chunk
#define NDC    (DIM / BK)          // 8 K-steps
#define NGRAN  (NCHUNK * 2)        // 16 granules of 256 cols (chunk x chalf)

typedef float    f32x4 __attribute__((ext_vector_type(4)));
typedef _Float16 f16x8 __attribute__((ext_vector_type(8)));

__device__ __forceinline__ unsigned umin_(unsigned a, unsigned b) { return a < b ? a : b; }
__device__ __forceinline__ unsigned umax_(unsigned a, unsigned b) { return a > b ? a : b; }

// order-preserving float->uint key
__device__ __forceinline__ unsigned fkey(float f) {
    unsigned b = __float_as_uint(f);
    return (b & 0x80000000u) ? ~b : (b | 0x80000000u);
}
__device__ __forceinline__ float fkey_inv(unsigned k) {
    unsigned b = (k & 0x80000000u) ? (k ^ 0x80000000u) : ~k;
    return __uint_as_float(b);
}
__device__ __forceinline__ unsigned short f2h(float f) {
    union { _Float16 h; unsigned short u; } cv;
    cv.h = (_Float16)f;            // v_cvt_f16_f32, RNE
    return cv.u;
}

// sorted top-8 insert by (value, index) lexicographic
__device__ __forceinline__ void ins8(float w, int j, float v[8], int id[8]) {
    if (w < v[7] || (w == v[7] && j < id[7])) {
        v[7] = w; id[7] = j;
#pragma unroll
        for (int k = 7; k > 0; --k) {
            if (v[k] < v[k-1] || (v[k] == v[k-1] && id[k] < id[k-1])) {
                float tv = v[k]; v[k] = v[k-1]; v[k-1] = tv;
                int ti = id[k]; id[k] = id[k-1]; id[k-1] = ti;
            }
        }
    }
}

// ---- prep: fp16 cast + row sumsq (fp64->fp32) + buffer init, fused ----
__global__ __launch_bounds__(256) void vq_prep_kernel(
        const float* __restrict__ x, const float* __restrict__ cb,
        unsigned short* __restrict__ xh, unsigned short* __restrict__ ch,
        float* __restrict__ xsq, float* __restrict__ csq,
        unsigned* __restrict__ colmin_g, unsigned* __restrict__ active,
        double* __restrict__ accum) {
    const int b = blockIdx.x, t = threadIdx.x;
    if (b < KCODES / 256) {
        int i = b * 256 + t;
        colmin_g[i] = 0xFFFFFFFFu; active[i] = 0u;
        if (i == 0) accum[0] = 0.0;
    }
    const size_t NX = (size_t)N_ROWS * DIM;
    size_t e = (size_t)b * 1024 + (size_t)t * 4;
    const float* src; unsigned short* dst; float* sq; size_t off;
    if (e < NX) { src = x;  dst = xh; sq = xsq; off = e; }
    else        { src = cb; dst = ch; sq = csq; off = e - NX; }
    float4 v = *(const float4*)(src + off);
    ushort4 h;
    h.x = f2h(v.x); h.y = f2h(v.y); h.z = f2h(v.z); h.w = f2h(v.w);
    *(ushort4*)(dst + off) = h;
    double s = (double)v.x * v.x + (double)v.y * v.y
             + (double)v.z * v.z + (double)v.w * v.w;
    for (int o = 32; o; o >>= 1) s += __shfl_down(s, o);
    if ((t & 63) == 0) sq[off >> 8] = (float)s;
}

// ---- MFMA candidate GEMM, barrier-free, packed-key epilogue (R9, unchanged).
// grid = (N_ROWS/TM, NCHUNK), 256 thr (4 waves, 2x2 of 64x64).
__global__ __launch_bounds__(256, 2) void vq_gemm_kernel(
        const unsigned short* __restrict__ xh_g, const unsigned short* __restrict__ ch_g,
        const float* __restrict__ xsq, const float* __restrict__ csq,
        unsigned* __restrict__ colmin_g, uint2* __restrict__ top2_out) {
    __shared__ float xsq_l[128];

    const int t = threadIdx.x;
    const int wave = t >> 6, lane = t & 63, quad = lane >> 4, L = lane & 15;
    const int whalf = wave >> 1, chalf = wave & 1;
    const int row0  = blockIdx.x * TM;
    const int code0 = blockIdx.y * KC;

    if (t < 128) xsq_l[t] = xsq[row0 + t];
    __syncthreads();
    float xsqr[16];
#pragma unroll
    for (int mt = 0; mt < 4; ++mt)
#pragma unroll
        for (int r = 0; r < 4; ++r)
            xsqr[mt * 4 + r] = xsq_l[whalf * 64 + mt * 16 + quad * 4 + r];

    const unsigned short* abase =
        xh_g + ((size_t)(row0 + whalf * 64 + L) * DIM + quad * 8);

    unsigned u1[16], u2[16];   // packed (quantized score | col9) running top-2
#pragma unroll
    for (int i = 0; i < 16; ++i) { u1[i] = 0xFFFFFFFFu; u2[i] = 0xFFFFFFFFu; }

    for (int kt = 0; kt < NKT; ++kt) {
        const int cb0 = code0 + kt * TN;
        const unsigned short* bbase =
            ch_g + ((size_t)(cb0 + chalf * 64 + L) * DIM + quad * 8);
        f32x4 acc[4][4];
#pragma unroll
        for (int mt = 0; mt < 4; ++mt)
#pragma unroll
            for (int nt = 0; nt < 4; ++nt) acc[mt][nt] = (f32x4){0.f, 0.f, 0.f, 0.f};

#pragma unroll
        for (int dc = 0; dc < NDC; ++dc) {
            f16x8 af[4], bf[4];
#pragma unroll
            for (int mt = 0; mt < 4; ++mt)
                af[mt] = *(const f16x8*)(abase + (size_t)mt * 16 * DIM + dc * BK);
#pragma unroll
            for (int nt = 0; nt < 4; ++nt)
                bf[nt] = *(const f16x8*)(bbase + (size_t)nt * 16 * DIM + dc * BK);
#pragma unroll
            for (int mt = 0; mt < 4; ++mt)
#pragma unroll
                for (int nt = 0; nt < 4; ++nt)
                    acc[mt][nt] = __builtin_amdgcn_mfma_f32_16x16x32_f16(
                        af[mt], bf[nt], acc[mt][nt], 0, 0, 0);
        }

        // ---- epilogue: packed-key top-2 upkeep + column-min ----
        float csq4[4]; unsigned colf[4];
        float dmin[4] = {3.4e38f, 3.4e38f, 3.4e38f, 3.4e38f};
#pragma unroll
        for (int nt = 0; nt < 4; ++nt) {
            csq4[nt] = csq[cb0 + chalf * 64 + nt * 16 + L];
            colf[nt] = (unsigned)(kt * 128 + chalf * 64 + nt * 16 + L);
        }
#pragma unroll
        for (int mt = 0; mt < 4; ++mt) {
#pragma unroll
            for (int reg = 0; reg < 4; ++reg) {
                const int i = mt * 4 + reg;
#pragma unroll
                for (int nt = 0; nt < 4; ++nt) {
                    float s = fmaf(-2.0f, acc[mt][nt][reg], csq4[nt]);
                    unsigned key = (fkey(s) & 0xFFFFFE00u) | colf[nt];
                    unsigned lo = umin_(u1[i], key);
                    u2[i] = umin_(u2[i], umax_(u1[i], key));
                    u1[i] = lo;
                    dmin[nt] = fminf(dmin[nt], xsqr[i] + s);
                }
            }
        }
#pragma unroll
        for (int nt = 0; nt < 4; ++nt) {
            unsigned dk = fkey(dmin[nt]);
            dk = umin_(dk, (unsigned)__shfl_xor((int)dk, 16));
            dk = umin_(dk, (unsigned)__shfl_xor((int)dk, 32));
            if (quad == 0)
                atomicMin(&colmin_g[cb0 + chalf * 64 + nt * 16 + L], dk);
        }
    }

    // ---- once per block: butterfly-merge top-2 across the 16 L-lanes ----
#pragma unroll
    for (int i = 0; i < 16; ++i) {
#pragma unroll
        for (int st = 1; st < 16; st <<= 1) {
            unsigned w1 = (unsigned)__shfl_xor((int)u1[i], st);
            unsigned w2 = (unsigned)__shfl_xor((int)u2[i], st);
            unsigned a = umin_(u1[i], w1), b = umax_(u1[i], w1);
            u1[i] = a;
            u2[i] = umin_(umin_(u2[i], w2), b);
        }
    }
    if (L == 0) {
        const size_t gbase = (size_t)(blockIdx.y * 2 + chalf) * N_ROWS;
#pragma unroll
        for (int mt = 0; mt < 4; ++mt)
#pragma unroll
            for (int reg = 0; reg < 4; ++reg) {
                const int row = row0 + whalf * 64 + mt * 16 + quad * 4 + reg;
                top2_out[gbase + row] = make_uint2(u1[mt * 4 + reg], u2[mt * 4 + reg]);
            }
    }
}

// ---- refine + gather + MSE, fused. grid = N_ROWS/4, 1 wave per row. ----
// R10: no dynamic array indexing anywhere (no scratch). Fast path: candidate
// gap > 1e-2 (>> 11 sigma of fp16-score noise + 2.4e-4 key quantization) =>
// winner certain, no fp64. Slow path: all 8 candidates, fully unrolled fp64
// re-score, token = lowest index within 0.75*ulp_fp32(Dmin).
__global__ __launch_bounds__(256) void vq_refine_kernel(
        const float* __restrict__ x, const float* __restrict__ cb,
        const uint2* __restrict__ top2, unsigned* __restrict__ active,
        float* __restrict__ out, double* __restrict__ accum) {
    __shared__ double wsum[4];
    const int wave = threadIdx.x >> 6, lane = threadIdx.x & 63;
    const int row  = blockIdx.x * 4 + wave;

    float v[8]; int id[8];
#pragma unroll
    for (int k = 0; k < 8; ++k) { v[k] = 3.4e38f; id[k] = 0x7FFFFFFF; }
#pragma unroll
    for (int g = 0; g < NGRAN; ++g) {
        uint2 e = top2[(size_t)g * N_ROWS + row];
        const int cbase = (g >> 1) * KC;
        ins8(fkey_inv(e.x & 0xFFFFFE00u), cbase + (int)(e.x & 0x1FFu), v, id);
        ins8(fkey_inv(e.y & 0xFFFFFE00u), cbase + (int)(e.y & 0x1FFu), v, id);
    }

    float4 xv = ((const float4*)(x + (size_t)row * DIM))[lane];
    int tok;
    if (v[1] > v[0] + 1.0e-2f) {
        // certain winner (wave-uniform branch), no fp64 needed
        tok = id[0];
    } else {
        // slow path: exact fp64 for all 8 candidates, fixed bounds, registers
        double xs64 = (double)xv.x * xv.x + (double)xv.y * xv.y
                    + (double)xv.z * xv.z + (double)xv.w * xv.w;
        double dd[8], cc2[8];
#pragma unroll
        for (int k = 0; k < 8; ++k) {
            float4 c4 = ((const float4*)(cb + (size_t)id[k] * DIM))[lane];
            dd[k]  = (double)xv.x * c4.x + (double)xv.y * c4.y
                   + (double)xv.z * c4.z + (double)xv.w * c4.w;
            cc2[k] = (double)c4.x * c4.x + (double)c4.y * c4.y
                   + (double)c4.z * c4.z + (double)c4.w * c4.w;
        }
#pragma unroll
        for (int o = 32; o; o >>= 1) {
            xs64 += __shfl_down(xs64, o);
#pragma unroll
            for (int k = 0; k < 8; ++k) {
                dd[k]  += __shfl_down(dd[k], o);
                cc2[k] += __shfl_down(cc2[k], o);
            }
        }
        if (lane == 0) {
            double D[8], Dmin = 1e300;
#pragma unroll
            for (int k = 0; k < 8; ++k) {
                D[k] = xs64 + cc2[k] - 2.0 * dd[k];
                Dmin = fmin(Dmin, D[k]);
            }
            int e2; frexp(Dmin, &e2);
            double U   = ldexp(1.0, e2 - 1 - 23);     // ulp_fp32(Dmin)
            double thr = Dmin + 0.75 * U;
            tok = 0x7FFFFFFF;
#pragma unroll
            for (int k = 0; k < 8; ++k)
                if (D[k] <= thr && id[k] < tok) tok = id[k];
        }
        tok = __shfl(tok, 0);
    }

    if (lane == 0) active[tok] = 1u;
    float4 sel = ((const float4*)(cb + (size_t)tok * DIM))[lane];
    ((float4*)out)[(size_t)row * 64 + lane] = sel;
    float dx = sel.x - xv.x, dy = sel.y - xv.y, dz = sel.z - xv.z, dw = sel.w - xv.w;
    float s = dx * dx + dy * dy + dz * dz + dw * dw;
    for (int o = 32; o; o >>= 1) s += __shfl_down(s, o);
    if (lane == 0) wsum[wave] = (double)s;
    __syncthreads();
    if (threadIdx.x == 0) atomicAdd(accum, wsum[0] + wsum[1] + wsum[2] + wsum[3]);
}

// ---- entropy term over inactive classes + final scalar loss ----
__global__ __launch_bounds__(256) void vq_final_kernel(
        const unsigned* __restrict__ colmin_g, const unsigned* __restrict__ active,
        const double* __restrict__ accum, float* __restrict__ out) {
    __shared__ double red[256];
    double s = 0.0;
    for (int k = threadIdx.x; k < KCODES; k += 256)
        if (active[k] == 0u) s += (double)fkey_inv(colmin_g[k]);
    red[threadIdx.x] = s;
    __syncthreads();
    for (int o = 128; o; o >>= 1) {
        if (threadIdx.x < o) red[threadIdx.x] += red[threadIdx.x + o];
        __syncthreads();
    }
    if (threadIdx.x == 0) {
        double loss = 1.25 * (accum[0] / (double)((size_t)N_ROWS * DIM))
                    + 0.02 * (red[0] / (double)KCODES);
        out[(size_t)N_ROWS * DIM] = (float)loss;
    }
}

extern "C" void kernel_launch(void* const* d_in, const int* in_sizes, int n_in,
                              void* d_out, int out_size, void* d_ws, size_t ws_size,
                              hipStream_t stream) {
    const float* x  = (const float*)d_in[0];   // [16384, 256]
    const float* cb = (const float*)d_in[1];   // [4096, 256]
    float* out = (float*)d_out;                // [16384*256] ++ [1] loss

    char* ws = (char*)d_ws;
    float*    xsq    = (float*)(ws + 0);                       // 64 KB
    float*    csq    = (float*)(ws + 65536);                   // 16 KB
    unsigned* colmin = (unsigned*)(ws + 81920);                // 16 KB
    unsigned* active = (unsigned*)(ws + 98304);                // 16 KB
    double*   accum  = (double*)(ws + 114688);                 // 256 B
    uint2*    top2   = (uint2*)(ws + 131072);                  // 2 MB (16 granules)
    unsigned short* xh_g = (unsigned short*)(ws + 2228224);    // 8 MB
    unsigned short* ch_g = (unsigned short*)(ws + 10616832);   // 2 MB (~12.6 MB)

    vq_prep_kernel<<<((N_ROWS + KCODES) * DIM) / 1024, 256, 0, stream>>>(
        x, cb, xh_g, ch_g, xsq, csq, colmin, active, accum);
    vq_gemm_kernel<<<dim3(N_ROWS / TM, NCHUNK), 256, 0, stream>>>(
        xh_g, ch_g, xsq, csq, colmin, top2);
    vq_refine_kernel<<<N_ROWS / 4, 256, 0, stream>>>(
        x, cb, top2, active, out, accum);
    vq_final_kernel<<<1, 256, 0, stream>>>(colmin, active, accum, out);
}

// Round 11
// 271.717 us; speedup vs baseline: 2.3255x; 1.0261x over previous
//
#include <hip/hip_runtime.h>
#include <stdint.h>

// ---------------------------------------------------------------------------
// VectorQuantizer: argmin_k ||x_n - c_k||^2 + straight-through out + losses.
//
// Token semantics (R4/R5/R7/R9-verified): candidates by continuous score
// s = ||c||^2 - 2 x.c via fp16 MFMA; exact fp64 re-score; token = lowest
// index within 0.75*ulp_fp32(Dmin) of the minimum.
//
// R9: packed-key epilogue -> gemm 197->129us. R10: scratch-free refine ->
// total 309->279us.
// R11: gemm counters showed 56MB WRITE / 39MB FETCH vs ~16MB of real data --
// the 1M cross-XCD colmin atomicMins were forcing ~64B-granularity ownership
// traffic. Replaced with per-block LDS colmin + private colmin_part[rowblock]
// slice (plain coalesced stores, zero global atomics); final kernel (16
// blocks + finisher counter) folds the 128-way reduction + entropy sum.
// ---------------------------------------------------------------------------

#define N_ROWS 16384
#define DIM    256
#define KCODES 4096
#define NCHUNK 8
#define KC     (KCODES / NCHUNK)   // 512 codes per chunk
#define TM     128                 // rows per block tile
#define TN     128                 // codes per code-tile
#define BK     32                  // K per dc step
#define NKT    (KC / TN)           // 4 code tiles per chunk
#define NDC    (DIM / BK)          // 8 K-steps
#define NGRAN  (NCHUNK * 2)        // 16 granules of 256 cols (chunk x chalf)
#define NRB    (N_ROWS / TM)       // 128 row-blocks

typedef float    f32x4 __attribute__((ext_vector_type(4)));
typedef _Float16 f16x8 __attribute__((ext_vector_type(8)));

__device__ __forceinline__ unsigned umin_(unsigned a, unsigned b) { return a < b ? a : b; }
__device__ __forceinline__ unsigned umax_(unsigned a, unsigned b) { return a > b ? a : b; }

// order-preserving float->uint key
__device__ __forceinline__ unsigned fkey(float f) {
    unsigned b = __float_as_uint(f);
    return (b & 0x80000000u) ? ~b : (b | 0x80000000u);
}
__device__ __forceinline__ float fkey_inv(unsigned k) {
    unsigned b = (k & 0x80000000u) ? (k ^ 0x80000000u) : ~k;
    return __uint_as_float(b);
}
__device__ __forceinline__ unsigned short f2h(float f) {
    union { _Float16 h; unsigned short u; } cv;
    cv.h = (_Float16)f;            // v_cvt_f16_f32, RNE
    return cv.u;
}

// sorted top-8 insert by (value, index) lexicographic
__device__ __forceinline__ void ins8(float w, int j, float v[8], int id[8]) {
    if (w < v[7] || (w == v[7] && j < id[7])) {
        v[7] = w; id[7] = j;
#pragma unroll
        for (int k = 7; k > 0; --k) {
            if (v[k] < v[k-1] || (v[k] == v[k-1] && id[k] < id[k-1])) {
                float tv = v[k]; v[k] = v[k-1]; v[k-1] = tv;
                int ti = id[k]; id[k] = id[k-1]; id[k-1] = ti;
            }
        }
    }
}

// ---- prep: fp16 cast + row sumsq (fp64->fp32) + buffer init, fused ----
__global__ __launch_bounds__(256) void vq_prep_kernel(
        const float* __restrict__ x, const float* __restrict__ cb,
        unsigned short* __restrict__ xh, unsigned short* __restrict__ ch,
        float* __restrict__ xsq, float* __restrict__ csq,
        unsigned* __restrict__ active, double* __restrict__ accum,
        unsigned* __restrict__ counter) {
    const int b = blockIdx.x, t = threadIdx.x;
    if (b < KCODES / 256) {
        int i = b * 256 + t;
        active[i] = 0u;
        if (i == 0) { accum[0] = 0.0; accum[1] = 0.0; counter[0] = 0u; }
    }
    const size_t NX = (size_t)N_ROWS * DIM;
    size_t e = (size_t)b * 1024 + (size_t)t * 4;
    const float* src; unsigned short* dst; float* sq; size_t off;
    if (e < NX) { src = x;  dst = xh; sq = xsq; off = e; }
    else        { src = cb; dst = ch; sq = csq; off = e - NX; }
    float4 v = *(const float4*)(src + off);
    ushort4 h;
    h.x = f2h(v.x); h.y = f2h(v.y); h.z = f2h(v.z); h.w = f2h(v.w);
    *(ushort4*)(dst + off) = h;
    double s = (double)v.x * v.x + (double)v.y * v.y
             + (double)v.z * v.z + (double)v.w * v.w;
    for (int o = 32; o; o >>= 1) s += __shfl_down(s, o);
    if ((t & 63) == 0) sq[off >> 8] = (float)s;
}

// ---- MFMA candidate GEMM, barrier-free K-loop, packed-key epilogue.
// grid = (NRB, NCHUNK), 256 thr (4 waves, 2x2 of 64x64).
// R11: colmin via LDS + private colmin_part[rowblock] slice (no global atomics).
__global__ __launch_bounds__(256, 2) void vq_gemm_kernel(
        const unsigned short* __restrict__ xh_g, const unsigned short* __restrict__ ch_g,
        const float* __restrict__ xsq, const float* __restrict__ csq,
        unsigned* __restrict__ colmin_part, uint2* __restrict__ top2_out) {
    __shared__ float    xsq_l[128];
    __shared__ unsigned colmin_l[KC];

    const int t = threadIdx.x;
    const int wave = t >> 6, lane = t & 63, quad = lane >> 4, L = lane & 15;
    const int whalf = wave >> 1, chalf = wave & 1;
    const int row0  = blockIdx.x * TM;
    const int code0 = blockIdx.y * KC;

    if (t < 128) xsq_l[t] = xsq[row0 + t];
    colmin_l[t] = 0xFFFFFFFFu; colmin_l[t + 256] = 0xFFFFFFFFu;
    __syncthreads();
    float xsqr[16];
#pragma unroll
    for (int mt = 0; mt < 4; ++mt)
#pragma unroll
        for (int r = 0; r < 4; ++r)
            xsqr[mt * 4 + r] = xsq_l[whalf * 64 + mt * 16 + quad * 4 + r];

    const unsigned short* abase =
        xh_g + ((size_t)(row0 + whalf * 64 + L) * DIM + quad * 8);

    unsigned u1[16], u2[16];   // packed (quantized score | col9) running top-2
#pragma unroll
    for (int i = 0; i < 16; ++i) { u1[i] = 0xFFFFFFFFu; u2[i] = 0xFFFFFFFFu; }

    for (int kt = 0; kt < NKT; ++kt) {
        const int cb0 = code0 + kt * TN;
        const unsigned short* bbase =
            ch_g + ((size_t)(cb0 + chalf * 64 + L) * DIM + quad * 8);
        f32x4 acc[4][4];
#pragma unroll
        for (int mt = 0; mt < 4; ++mt)
#pragma unroll
            for (int nt = 0; nt < 4; ++nt) acc[mt][nt] = (f32x4){0.f, 0.f, 0.f, 0.f};

#pragma unroll
        for (int dc = 0; dc < NDC; ++dc) {
            f16x8 af[4], bf[4];
#pragma unroll
            for (int mt = 0; mt < 4; ++mt)
                af[mt] = *(const f16x8*)(abase + (size_t)mt * 16 * DIM + dc * BK);
#pragma unroll
            for (int nt = 0; nt < 4; ++nt)
                bf[nt] = *(const f16x8*)(bbase + (size_t)nt * 16 * DIM + dc * BK);
#pragma unroll
            for (int mt = 0; mt < 4; ++mt)
#pragma unroll
                for (int nt = 0; nt < 4; ++nt)
                    acc[mt][nt] = __builtin_amdgcn_mfma_f32_16x16x32_f16(
                        af[mt], bf[nt], acc[mt][nt], 0, 0, 0);
        }

        // ---- epilogue: packed-key top-2 upkeep + column-min (LDS) ----
        float csq4[4]; unsigned colf[4];
        float dmin[4] = {3.4e38f, 3.4e38f, 3.4e38f, 3.4e38f};
#pragma unroll
        for (int nt = 0; nt < 4; ++nt) {
            csq4[nt] = csq[cb0 + chalf * 64 + nt * 16 + L];
            colf[nt] = (unsigned)(kt * 128 + chalf * 64 + nt * 16 + L);
        }
#pragma unroll
        for (int mt = 0; mt < 4; ++mt) {
#pragma unroll
            for (int reg = 0; reg < 4; ++reg) {
                const int i = mt * 4 + reg;
#pragma unroll
                for (int nt = 0; nt < 4; ++nt) {
                    float s = fmaf(-2.0f, acc[mt][nt][reg], csq4[nt]);
                    unsigned key = (fkey(s) & 0xFFFFFE00u) | colf[nt];
                    unsigned lo = umin_(u1[i], key);
                    u2[i] = umin_(u2[i], umax_(u1[i], key));
                    u1[i] = lo;
                    dmin[nt] = fminf(dmin[nt], xsqr[i] + s);
                }
            }
        }
#pragma unroll
        for (int nt = 0; nt < 4; ++nt) {
            unsigned dk = fkey(dmin[nt]);
            dk = umin_(dk, (unsigned)__shfl_xor((int)dk, 16));
            dk = umin_(dk, (unsigned)__shfl_xor((int)dk, 32));
            if (quad == 0)
                atomicMin(&colmin_l[kt * TN + chalf * 64 + nt * 16 + L], dk);
        }
    }

    // ---- once per block: butterfly-merge top-2 across the 16 L-lanes ----
#pragma unroll
    for (int i = 0; i < 16; ++i) {
#pragma unroll
        for (int st = 1; st < 16; st <<= 1) {
            unsigned w1 = (unsigned)__shfl_xor((int)u1[i], st);
            unsigned w2 = (unsigned)__shfl_xor((int)u2[i], st);
            unsigned a = umin_(u1[i], w1), b = umax_(u1[i], w1);
            u1[i] = a;
            u2[i] = umin_(umin_(u2[i], w2), b);
        }
    }
    if (L == 0) {
        const size_t gbase = (size_t)(blockIdx.y * 2 + chalf) * N_ROWS;
#pragma unroll
        for (int mt = 0; mt < 4; ++mt)
#pragma unroll
            for (int reg = 0; reg < 4; ++reg) {
                const int row = row0 + whalf * 64 + mt * 16 + quad * 4 + reg;
                top2_out[gbase + row] = make_uint2(u1[mt * 4 + reg], u2[mt * 4 + reg]);
            }
    }

    // ---- flush block-local colmin to private slice (plain stores) ----
    __syncthreads();
    unsigned* cp = colmin_part + (size_t)blockIdx.x * KCODES + code0;
    cp[t]       = colmin_l[t];
    cp[t + 256] = colmin_l[t + 256];
}

// ---- refine + gather + MSE, fused. grid = N_ROWS/4, 1 wave per row. ----
// Fast path: candidate gap > 1e-2 => winner certain, no fp64. Slow path:
// all 8 candidates, fully unrolled fp64 re-score, token = lowest index
// within 0.75*ulp_fp32(Dmin). No dynamic indexing (no scratch).
__global__ __launch_bounds__(256) void vq_refine_kernel(
        const float* __restrict__ x, const float* __restrict__ cb,
        const uint2* __restrict__ top2, unsigned* __restrict__ active,
        float* __restrict__ out, double* __restrict__ accum) {
    __shared__ double wsum[4];
    const int wave = threadIdx.x >> 6, lane = threadIdx.x & 63;
    const int row  = blockIdx.x * 4 + wave;

    float v[8]; int id[8];
#pragma unroll
    for (int k = 0; k < 8; ++k) { v[k] = 3.4e38f; id[k] = 0x7FFFFFFF; }
#pragma unroll
    for (int g = 0; g < NGRAN; ++g) {
        uint2 e = top2[(size_t)g * N_ROWS + row];
        const int cbase = (g >> 1) * KC;
        ins8(fkey_inv(e.x & 0xFFFFFE00u), cbase + (int)(e.x & 0x1FFu), v, id);
        ins8(fkey_inv(e.y & 0xFFFFFE00u), cbase + (int)(e.y & 0x1FFu), v, id);
    }

    float4 xv = ((const float4*)(x + (size_t)row * DIM))[lane];
    int tok;
    if (v[1] > v[0] + 1.0e-2f) {
        tok = id[0];
    } else {
        double xs64 = (double)xv.x * xv.x + (double)xv.y * xv.y
                    + (double)xv.z * xv.z + (double)xv.w * xv.w;
        double dd[8], cc2[8];
#pragma unroll
        for (int k = 0; k < 8; ++k) {
            float4 c4 = ((const float4*)(cb + (size_t)id[k] * DIM))[lane];
            dd[k]  = (double)xv.x * c4.x + (double)xv.y * c4.y
                   + (double)xv.z * c4.z + (double)xv.w * c4.w;
            cc2[k] = (double)c4.x * c4.x + (double)c4.y * c4.y
                   + (double)c4.z * c4.z + (double)c4.w * c4.w;
        }
#pragma unroll
        for (int o = 32; o; o >>= 1) {
            xs64 += __shfl_down(xs64, o);
#pragma unroll
            for (int k = 0; k < 8; ++k) {
                dd[k]  += __shfl_down(dd[k], o);
                cc2[k] += __shfl_down(cc2[k], o);
            }
        }
        if (lane == 0) {
            double D[8], Dmin = 1e300;
#pragma unroll
            for (int k = 0; k < 8; ++k) {
                D[k] = xs64 + cc2[k] - 2.0 * dd[k];
                Dmin = fmin(Dmin, D[k]);
            }
            int e2; frexp(Dmin, &e2);
            double U   = ldexp(1.0, e2 - 1 - 23);     // ulp_fp32(Dmin)
            double thr = Dmin + 0.75 * U;
            tok = 0x7FFFFFFF;
#pragma unroll
            for (int k = 0; k < 8; ++k)
                if (D[k] <= thr && id[k] < tok) tok = id[k];
        }
        tok = __shfl(tok, 0);
    }

    if (lane == 0) active[tok] = 1u;
    float4 sel = ((const float4*)(cb + (size_t)tok * DIM))[lane];
    ((float4*)out)[(size_t)row * 64 + lane] = sel;
    float dx = sel.x - xv.x, dy = sel.y - xv.y, dz = sel.z - xv.z, dw = sel.w - xv.w;
    float s = dx * dx + dy * dy + dz * dz + dw * dw;
    for (int o = 32; o; o >>= 1) s += __shfl_down(s, o);
    if (lane == 0) wsum[wave] = (double)s;
    __syncthreads();
    if (threadIdx.x == 0) atomicAdd(accum, wsum[0] + wsum[1] + wsum[2] + wsum[3]);
}

// ---- final: 128-way colmin reduction + entropy + loss. grid = 16 blocks.
// Each block reduces 256 codes over the 128 row-block partials, adds its
// inactive-code entropy partial; the 16th finisher computes the loss.
__global__ __launch_bounds__(256) void vq_final_kernel(
        const unsigned* __restrict__ colmin_part, const unsigned* __restrict__ active,
        double* __restrict__ accum, unsigned* __restrict__ counter,
        float* __restrict__ out) {
    __shared__ double red[256];
    const int t = threadIdx.x;
    const int c = blockIdx.x * 256 + t;
    unsigned m = 0xFFFFFFFFu;
#pragma unroll 8
    for (int rb = 0; rb < NRB; ++rb)
        m = umin_(m, colmin_part[(size_t)rb * KCODES + c]);
    red[t] = (active[c] == 0u) ? (double)fkey_inv(m) : 0.0;
    __syncthreads();
    for (int o = 128; o; o >>= 1) {
        if (t < o) red[t] += red[t + o];
        __syncthreads();
    }
    if (t == 0) {
        atomicAdd(&accum[1], red[0]);
        __threadfence();
        unsigned old = atomicAdd(counter, 1u);
        if (old == 15u) {
            __threadfence();
            double ent = atomicAdd(&accum[1], 0.0);   // atomic read
            double loss = 1.25 * (accum[0] / (double)((size_t)N_ROWS * DIM))
                        + 0.02 * (ent / (double)KCODES);
            out[(size_t)N_ROWS * DIM] = (float)loss;
        }
    }
}

extern "C" void kernel_launch(void* const* d_in, const int* in_sizes, int n_in,
                              void* d_out, int out_size, void* d_ws, size_t ws_size,
                              hipStream_t stream) {
    const float* x  = (const float*)d_in[0];   // [16384, 256]
    const float* cb = (const float*)d_in[1];   // [4096, 256]
    float* out = (float*)d_out;                // [16384*256] ++ [1] loss

    char* ws = (char*)d_ws;
    float*    xsq     = (float*)(ws + 0);                      // 64 KB
    float*    csq     = (float*)(ws + 65536);                  // 16 KB
    unsigned* active  = (unsigned*)(ws + 81920);               // 16 KB
    double*   accum   = (double*)(ws + 98304);                 // 256 B (mse, entropy)
    unsigned* counter = (unsigned*)(ws + 98560);               // 64 B
    uint2*    top2    = (uint2*)(ws + 131072);                 // 2 MB (16 granules)
    unsigned* cpart   = (unsigned*)(ws + 2228224);             // 2 MB (128 x 4096)
    unsigned short* xh_g = (unsigned short*)(ws + 4325376);    // 8 MB
    unsigned short* ch_g = (unsigned short*)(ws + 12713984);   // 2 MB (~14.2 MB)

    vq_prep_kernel<<<((N_ROWS + KCODES) * DIM) / 1024, 256, 0, stream>>>(
        x, cb, xh_g, ch_g, xsq, csq, active, accum, counter);
    vq_gemm_kernel<<<dim3(NRB, NCHUNK), 256, 0, stream>>>(
        xh_g, ch_g, xsq, csq, cpart, top2);
    vq_refine_kernel<<<N_ROWS / 4, 256, 0, stream>>>(
        x, cb, top2, active, out, accum);
    vq_final_kernel<<<KCODES / 256, 256, 0, stream>>>(
        cpart, active, accum, counter, out);
}